// Round 18
// baseline (261.852 us; speedup 1.0000x reference)
//
#include <hip/hip_runtime.h>
#include <hip/hip_bf16.h>
#include <cstddef>

// Problem constants (fixed by setup_inputs)
#define TOTAL   1536
#define HIDDEN  1024
#define HK      8
#define HV      16
#define DK      64
#define DV      64
#define KSZ     4
#define KEY_DIM 512
#define VAL_DIM 1024
#define CONV_DIM 2048
#define NSEQ    4
#define MAXCH   27    // max total chunks
#define NMIX    3072  // merged qkv+z output width

typedef _Float16 f16;
typedef __attribute__((ext_vector_type(8))) _Float16 f16x8;
typedef __attribute__((ext_vector_type(4))) _Float16 f16x4;
typedef __attribute__((ext_vector_type(4))) float f32x4;

__device__ __forceinline__ f16x8 cvt8(float4 a, float4 b) {
    f16x8 h;
    h[0] = (f16)a.x; h[1] = (f16)a.y; h[2] = (f16)a.z; h[3] = (f16)a.w;
    h[4] = (f16)b.x; h[5] = (f16)b.y; h[6] = (f16)b.z; h[7] = (f16)b.w;
    return h;
}

// ---------------------------------------------------------------------------
// GEMM 1: mixed3[M,NMIX] = H[M,K](f32) @ [Wqkv;Wz][NMIX,K](f32)^T -> f16.
// 128x128 tile, BK=64, 256 thr; fp32->f16 conversion fused into staging.
// ---------------------------------------------------------------------------
#define LDK 72
__global__ __launch_bounds__(256) void gemm_qkvz(const float* __restrict__ A,
                                                 const float* __restrict__ B0,
                                                 const float* __restrict__ B1,
                                                 f16* __restrict__ C,
                                                 int M, int N, int K) {
    __shared__ __align__(16) f16 As[128 * LDK];
    __shared__ __align__(16) f16 Bs[128 * LDK];
    const int tid = threadIdx.x;
    const int m0 = blockIdx.y * 128, n0 = blockIdx.x * 128;
    const int lane = tid & 63, w = tid >> 6;
    const int wm = (w >> 1) * 64, wn = (w & 1) * 64;
    const int fr = lane & 15;
    const int fk = (lane >> 4) * 8;
    const int sr = tid >> 1;
    const int sc = (tid & 1) * 32;

    const int brow = n0 + sr;   // 2048 % 128 == 0: tile never straddles B0/B1
    const float* bsrc = (brow < CONV_DIM) ? (B0 + (size_t)brow * K)
                                          : (B1 + (size_t)(brow - CONV_DIM) * K);

    f32x4 acc[4][4];
#pragma unroll
    for (int i = 0; i < 4; ++i)
#pragma unroll
        for (int j = 0; j < 4; ++j) acc[i][j] = (f32x4){0.f, 0.f, 0.f, 0.f};

    for (int kk = 0; kk < K; kk += 64) {
        const float* ga = A + (size_t)(m0 + sr) * K + kk + sc;
        const float* gb = bsrc + kk + sc;
        float4 av[8], bv[8];
#pragma unroll
        for (int i = 0; i < 8; ++i) {
            av[i] = *(const float4*)(ga + i * 4);
            bv[i] = *(const float4*)(gb + i * 4);
        }
        __syncthreads();
#pragma unroll
        for (int i = 0; i < 4; ++i) {
            *(f16x8*)&As[sr * LDK + sc + i * 8] = cvt8(av[2 * i], av[2 * i + 1]);
            *(f16x8*)&Bs[sr * LDK + sc + i * 8] = cvt8(bv[2 * i], bv[2 * i + 1]);
        }
        __syncthreads();

#pragma unroll
        for (int k2 = 0; k2 < 64; k2 += 32) {
            f16x8 af[4], bfr[4];
#pragma unroll
            for (int i = 0; i < 4; ++i)
                af[i] = *(const f16x8*)&As[(wm + i * 16 + fr) * LDK + k2 + fk];
#pragma unroll
            for (int j = 0; j < 4; ++j)
                bfr[j] = *(const f16x8*)&Bs[(wn + j * 16 + fr) * LDK + k2 + fk];
#pragma unroll
            for (int i = 0; i < 4; ++i)
#pragma unroll
                for (int j = 0; j < 4; ++j)
                    acc[i][j] = __builtin_amdgcn_mfma_f32_16x16x32_f16(
                        af[i], bfr[j], acc[i][j], 0, 0, 0);
        }
    }

    const int er = (lane >> 4) * 4;
#pragma unroll
    for (int i = 0; i < 4; ++i)
#pragma unroll
        for (int j = 0; j < 4; ++j) {
            const int col = n0 + wn + j * 16 + fr;
#pragma unroll
            for (int r = 0; r < 4; ++r) {
                const int row = m0 + wm + i * 16 + er + r;
                C[(size_t)row * N + col] = (f16)acc[i][j][r];
            }
        }
}

// ---------------------------------------------------------------------------
// GEMM 2: out[M,N](f32) = obf[M,K](f16) @ Wout[N,K](f32)^T.
// ---------------------------------------------------------------------------
__global__ __launch_bounds__(256) void gemm_out(const f16* __restrict__ A,
                                                const float* __restrict__ B,
                                                float* __restrict__ C,
                                                int M, int N, int K) {
    __shared__ __align__(16) f16 As[128 * LDK];
    __shared__ __align__(16) f16 Bs[128 * LDK];
    const int tid = threadIdx.x;
    const int m0 = blockIdx.y * 128, n0 = blockIdx.x * 128;
    const int lane = tid & 63, w = tid >> 6;
    const int wm = (w >> 1) * 64, wn = (w & 1) * 64;
    const int fr = lane & 15;
    const int fk = (lane >> 4) * 8;
    const int sr = tid >> 1;
    const int sc = (tid & 1) * 32;

    f32x4 acc[4][4];
#pragma unroll
    for (int i = 0; i < 4; ++i)
#pragma unroll
        for (int j = 0; j < 4; ++j) acc[i][j] = (f32x4){0.f, 0.f, 0.f, 0.f};

    for (int kk = 0; kk < K; kk += 64) {
        const f16* ga = A + (size_t)(m0 + sr) * K + kk + sc;
        const float* gb = B + (size_t)(n0 + sr) * K + kk + sc;
        uint4 a0 = *(const uint4*)(ga + 0);
        uint4 a1 = *(const uint4*)(ga + 8);
        uint4 a2 = *(const uint4*)(ga + 16);
        uint4 a3 = *(const uint4*)(ga + 24);
        float4 bv[8];
#pragma unroll
        for (int i = 0; i < 8; ++i) bv[i] = *(const float4*)(gb + i * 4);
        __syncthreads();
        *(uint4*)&As[sr * LDK + sc + 0]  = a0;
        *(uint4*)&As[sr * LDK + sc + 8]  = a1;
        *(uint4*)&As[sr * LDK + sc + 16] = a2;
        *(uint4*)&As[sr * LDK + sc + 24] = a3;
#pragma unroll
        for (int i = 0; i < 4; ++i)
            *(f16x8*)&Bs[sr * LDK + sc + i * 8] = cvt8(bv[2 * i], bv[2 * i + 1]);
        __syncthreads();

#pragma unroll
        for (int k2 = 0; k2 < 64; k2 += 32) {
            f16x8 af[4], bfr[4];
#pragma unroll
            for (int i = 0; i < 4; ++i)
                af[i] = *(const f16x8*)&As[(wm + i * 16 + fr) * LDK + k2 + fk];
#pragma unroll
            for (int j = 0; j < 4; ++j)
                bfr[j] = *(const f16x8*)&Bs[(wn + j * 16 + fr) * LDK + k2 + fk];
#pragma unroll
            for (int i = 0; i < 4; ++i)
#pragma unroll
                for (int j = 0; j < 4; ++j)
                    acc[i][j] = __builtin_amdgcn_mfma_f32_16x16x32_f16(
                        af[i], bfr[j], acc[i][j], 0, 0, 0);
        }
    }

    const int er = (lane >> 4) * 4;
#pragma unroll
    for (int i = 0; i < 4; ++i)
#pragma unroll
        for (int j = 0; j < 4; ++j) {
            const int col = n0 + wn + j * 16 + fr;
#pragma unroll
            for (int r = 0; r < 4; ++r) {
                const int row = m0 + wm + i * 16 + er + r;
                C[(size_t)row * N + col] = acc[i][j][r];
            }
        }
}

// ---------------------------------------------------------------------------
// Merged conv+proj. Block per token. (unchanged R17)
// ---------------------------------------------------------------------------
__global__ __launch_bounds__(256) void conv_proj(const f16* __restrict__ mixed3,
                                                 const float* __restrict__ cw,
                                                 const int* __restrict__ cu,
                                                 const float* __restrict__ H,
                                                 const float* __restrict__ Wb,
                                                 const float* __restrict__ Wa,
                                                 const float* __restrict__ dtb,
                                                 const float* __restrict__ Alog,
                                                 f16* __restrict__ qb,
                                                 f16* __restrict__ kb,
                                                 f16* __restrict__ vb,
                                                 float* __restrict__ betab,
                                                 float* __restrict__ lgb) {
    const int tok = blockIdx.x;
    const int tid = threadIdx.x;
    const int lane = tid & 63, w = tid >> 6;
    __shared__ float scale[16];

    int b = 0;
    for (int i = 1; i < NSEQ; ++i)
        if (tok >= cu[i]) b = i;
    const int pos = tok - cu[b];

#pragma unroll
    for (int it = 0; it < 8; ++it) {
        const int o = it * 4 + w;
        const float* wrow = (o < 16) ? (Wb + (size_t)o * HIDDEN)
                                     : (Wa + (size_t)(o - 16) * HIDDEN);
        float s = 0.f;
#pragma unroll
        for (int i = 0; i < 4; ++i) {
            float4 a = *(const float4*)&H[(size_t)tok * HIDDEN + i * 256 + lane * 4];
            float4 c = *(const float4*)&wrow[i * 256 + lane * 4];
            s += a.x * c.x + a.y * c.y + a.z * c.z + a.w * c.w;
        }
#pragma unroll
        for (int m = 1; m < 64; m <<= 1) s += __shfl_xor(s, m);
        if (lane == 0) {
            if (o < 16) {
                betab[tok * HV + o] = 1.f / (1.f + expf(-s));
            } else {
                const int hh = o - 16;
                float x = s + dtb[hh];
                float sp = (x > 20.f) ? x : log1pf(expf(x));
                lgb[tok * HV + hh] = -expf(Alog[hh]) * sp;
            }
        }
    }

    float4 yv[2];
#pragma unroll
    for (int it = 0; it < 2; ++it) {
        const int c0 = (tid + it * 256) * 4;
        float wf[4][4];
#pragma unroll
        for (int r = 0; r < 4; ++r) {
            float4 t4 = *(const float4*)&cw[(c0 + r) * 4];
            wf[r][0] = t4.x; wf[r][1] = t4.y; wf[r][2] = t4.z; wf[r][3] = t4.w;
        }
        float4 acc = {0.f, 0.f, 0.f, 0.f};
#pragma unroll
        for (int j = 0; j < KSZ; ++j) {
            const int off = j - (KSZ - 1);
            if (pos + off >= 0) {
                f16x4 xh = *(const f16x4*)&mixed3[(size_t)(tok + off) * NMIX + c0];
                acc.x += wf[0][j] * (float)xh[0]; acc.y += wf[1][j] * (float)xh[1];
                acc.z += wf[2][j] * (float)xh[2]; acc.w += wf[3][j] * (float)xh[3];
            }
        }
        float4 y;
        y.x = acc.x / (1.f + expf(-acc.x));
        y.y = acc.y / (1.f + expf(-acc.y));
        y.z = acc.z / (1.f + expf(-acc.z));
        y.w = acc.w / (1.f + expf(-acc.w));
        yv[it] = y;
        if (it == 0) {
            float p = y.x * y.x + y.y * y.y + y.z * y.z + y.w * y.w;
            p += __shfl_xor(p, 1);
            p += __shfl_xor(p, 2);
            p += __shfl_xor(p, 4);
            p += __shfl_xor(p, 8);
            if ((tid & 15) == 0) scale[tid >> 4] = rsqrtf(p + 1e-6f);
        }
    }
    __syncthreads();

#pragma unroll
    for (int it = 0; it < 2; ++it) {
        const int c0 = (tid + it * 256) * 4;
        float4 y = yv[it];
        if (c0 < KEY_DIM) {
            const float f = scale[c0 >> 6] * 0.125f;
            f16x4 r = {(f16)(y.x * f), (f16)(y.y * f), (f16)(y.z * f), (f16)(y.w * f)};
            *(f16x4*)&qb[(size_t)tok * KEY_DIM + c0] = r;
        } else if (c0 < 2 * KEY_DIM) {
            const float s = scale[c0 >> 6];
            f16x4 r = {(f16)(y.x * s), (f16)(y.y * s), (f16)(y.z * s), (f16)(y.w * s)};
            *(f16x4*)&kb[(size_t)tok * KEY_DIM + (c0 - KEY_DIM)] = r;
        } else {
            f16x4 r = {(f16)y.x, (f16)y.y, (f16)y.z, (f16)y.w};
            *(f16x4*)&vb[(size_t)tok * VAL_DIM + (c0 - 2 * KEY_DIM)] = r;
        }
    }
}

// ---------------------------------------------------------------------------
// Delta phase 1, MFMA. Block = (chunk, head). (unchanged)
// ---------------------------------------------------------------------------
#define SF 72   // f16 MFMA-array row stride
#define SA 68   // Am fp32 row stride
__global__ __launch_bounds__(256) void delta_phase1(
        const f16* __restrict__ qb, const f16* __restrict__ kb,
        const f16* __restrict__ vb, const float* __restrict__ lgb,
        const float* __restrict__ betab, const int* __restrict__ cu,
        float* __restrict__ ob, f16* __restrict__ Gg,
        f16* __restrict__ Hg, f16* __restrict__ Zg) {
    const int c = blockIdx.x >> 4;
    const int h = blockIdx.x & 15;
    const int hk = h >> 1;
    int b = -1, base = 0, t1 = 0, cs = 0;
    for (int i = 0; i < NSEQ; ++i) {
        int len = cu[i + 1] - cu[i];
        int nb = (len + 63) >> 6;
        if (b < 0) {
            if (c < cs + nb) { b = i; base = cu[i] + (c - cs) * 64; t1 = cu[i + 1]; }
            else cs += nb;
        }
    }
    if (b < 0) return;
    const size_t slot = (size_t)blockIdx.x * 4096;

    const int tid = threadIdx.x;
    const int lane = tid & 63, w = tid >> 6;
    const int fr = lane & 15;
    const int fk = (lane >> 4) * 8;
    const int er = (lane >> 4) * 4;

    __shared__ __align__(16) f16 Kl[64 * SF];    // [t][d]
    __shared__ __align__(16) f16 Ql[64 * SF];    // [t][d]
    __shared__ __align__(16) f16 KTd[64 * SF];   // [dk][t], pre-scaled by dsc[t]
    __shared__ __align__(16) f16 Xt[128 * SF];   // [col][t]
    __shared__ __align__(16) float Am[64 * SA];  // A fp32; later Pl f16
    __shared__ float cl[64], el[64], bl[64], lgl[64], dscl[64];
    f16* Pl = (f16*)Am;

    const int tt = tid >> 2;
    const int tau0 = base + tt;
    const bool valid = tau0 < t1;
    const f16x4 zh4 = {(f16)0.f, (f16)0.f, (f16)0.f, (f16)0.f};
    f16x4 kv[4], qv[4], vv[4];
#pragma unroll
    for (int u4 = 0; u4 < 4; ++u4) {
        const int d = ((tid & 3) << 2) + u4 * 16;
        kv[u4] = valid ? *(const f16x4*)&kb[(size_t)tau0 * KEY_DIM + hk * 64 + d] : zh4;
        qv[u4] = valid ? *(const f16x4*)&qb[(size_t)tau0 * KEY_DIM + hk * 64 + d] : zh4;
        vv[u4] = valid ? *(const f16x4*)&vb[(size_t)tau0 * VAL_DIM + h * 64 + d] : zh4;
    }
    if (tid < 64) {
        const int ta = base + tid;
        const bool v2 = ta < t1;
        lgl[tid] = v2 ? lgb[ta * HV + h] : 0.f;
        bl[tid]  = v2 ? betab[ta * HV + h] : 0.f;
    }
    __syncthreads();

    if (w == 0) {
        float x = lgl[lane];
#pragma unroll
        for (int off = 1; off < 64; off <<= 1) {
            float y = __shfl_up(x, off);
            if (lane >= off) x += y;
        }
        cl[lane] = x;
        el[lane] = expf(x);
        float c63 = __shfl(x, 63);
        dscl[lane] = expf(c63 - x);
    }
    __syncthreads();

    {
        const float bt = bl[tt], bet = bt * el[tt], ds = dscl[tt];
#pragma unroll
        for (int u4 = 0; u4 < 4; ++u4) {
            const int d = ((tid & 3) << 2) + u4 * 16;
            *(f16x4*)&Kl[tt * SF + d] = kv[u4];
            *(f16x4*)&Ql[tt * SF + d] = qv[u4];
#pragma unroll
            for (int e = 0; e < 4; ++e) {
                const float kf = (float)kv[u4][e];
                const float vf = (float)vv[u4][e];
                KTd[(d + e) * SF + tt] = (f16)(kf * ds);
                Xt[(d + e) * SF + tt] = (f16)(bt * vf);
                Xt[(64 + d + e) * SF + tt] = (f16)(bet * kf);
            }
        }
    }
    __syncthreads();

    // A-gram MFMA + decay -> Am fp32
    {
        f16x8 a0 = *(const f16x8*)&Kl[(16 * w + fr) * SF + fk];
        f16x8 a1 = *(const f16x8*)&Kl[(16 * w + fr) * SF + 32 + fk];
#pragma unroll
        for (int j = 0; j < 4; ++j) {
            f16x8 b0 = *(const f16x8*)&Kl[(16 * j + fr) * SF + fk];
            f16x8 b1 = *(const f16x8*)&Kl[(16 * j + fr) * SF + 32 + fk];
            f32x4 acc = {0.f, 0.f, 0.f, 0.f};
            acc = __builtin_amdgcn_mfma_f32_16x16x32_f16(a0, b0, acc, 0, 0, 0);
            acc = __builtin_amdgcn_mfma_f32_16x16x32_f16(a1, b1, acc, 0, 0, 0);
            const int s = 16 * j + fr;
#pragma unroll
            for (int r = 0; r < 4; ++r) {
                const int t = 16 * w + er + r;
                Am[t * SA + s] = (s < t) ? bl[t] * expf(cl[t] - cl[s]) * acc[r] : 0.f;
            }
        }
    }
    __syncthreads();

    // blocked fwd substitution on Xt (f16 storage, fp32 math)
#pragma unroll
    for (int ib = 0; ib < 4; ++ib) {
        if (tid < 128) {
            float xr[16];
#pragma unroll
            for (int i = 0; i < 16; ++i) {
                const int t = ib * 16 + i;
                float acc = (float)Xt[tid * SF + t];
#pragma unroll
                for (int s = 0; s < 16; ++s)
                    if (s < i) acc -= Am[t * SA + ib * 16 + s] * xr[s];
                xr[i] = acc;
                Xt[tid * SF + t] = (f16)acc;
            }
        }
        __syncthreads();
        if (ib < 3) {
            const int j = tid & 127;
            const int rh = tid >> 7;
            float us[16];
#pragma unroll
            for (int s = 0; s < 16; ++s) us[s] = (float)Xt[j * SF + ib * 16 + s];
            for (int r = (ib + 1) * 16 + rh; r < 64; r += 2) {
                float acc = (float)Xt[j * SF + r];
#pragma unroll
                for (int s = 0; s < 16; ++s)
                    acc -= Am[r * SA + ib * 16 + s] * us[s];
                Xt[j * SF + r] = (f16)acc;
            }
            __syncthreads();
        }
    }

    // P-gram MFMA -> Pl f16 (Am region; Am dead)
    {
        f16x8 a0 = *(const f16x8*)&Ql[(16 * w + fr) * SF + fk];
        f16x8 a1 = *(const f16x8*)&Ql[(16 * w + fr) * SF + 32 + fk];
        float pv[4][4];
#pragma unroll
        for (int j = 0; j < 4; ++j) {
            f16x8 b0 = *(const f16x8*)&Kl[(16 * j + fr) * SF + fk];
            f16x8 b1 = *(const f16x8*)&Kl[(16 * j + fr) * SF + 32 + fk];
            f32x4 acc = {0.f, 0.f, 0.f, 0.f};
            acc = __builtin_amdgcn_mfma_f32_16x16x32_f16(a0, b0, acc, 0, 0, 0);
            acc = __builtin_amdgcn_mfma_f32_16x16x32_f16(a1, b1, acc, 0, 0, 0);
            const int s = 16 * j + fr;
#pragma unroll
            for (int r = 0; r < 4; ++r) {
                const int t = 16 * w + er + r;
                pv[j][r] = (s <= t) ? expf(cl[t] - cl[s]) * acc[r] : 0.f;
            }
        }
#pragma unroll
        for (int j = 0; j < 4; ++j) {
            const int s = 16 * j + fr;
#pragma unroll
            for (int r = 0; r < 4; ++r)
                Pl[(16 * w + er + r) * SF + s] = (f16)pv[j][r];
        }
    }
    __syncthreads();

    // output MFMAs
    f16x8 pa0 = *(const f16x8*)&Pl[(16 * w + fr) * SF + fk];
    f16x8 pa1 = *(const f16x8*)&Pl[(16 * w + fr) * SF + 32 + fk];
    f16x8 ka0 = *(const f16x8*)&KTd[(16 * w + fr) * SF + fk];
    f16x8 ka1 = *(const f16x8*)&KTd[(16 * w + fr) * SF + 32 + fk];

#pragma unroll
    for (int j = 0; j < 4; ++j) {
        f16x8 b0 = *(const f16x8*)&Xt[(16 * j + fr) * SF + fk];
        f16x8 b1 = *(const f16x8*)&Xt[(16 * j + fr) * SF + 32 + fk];
        f32x4 acc = {0.f, 0.f, 0.f, 0.f};
        acc = __builtin_amdgcn_mfma_f32_16x16x32_f16(pa0, b0, acc, 0, 0, 0);
        acc = __builtin_amdgcn_mfma_f32_16x16x32_f16(pa1, b1, acc, 0, 0, 0);
        const int dv = 16 * j + fr;
#pragma unroll
        for (int r = 0; r < 4; ++r) {
            const int tau = base + 16 * w + er + r;
            if (tau < t1)
                ob[(size_t)tau * VAL_DIM + h * 64 + dv] = acc[r];
        }
    }
#pragma unroll
    for (int j = 0; j < 4; ++j) {
        f16x8 b0 = *(const f16x8*)&Xt[(64 + 16 * j + fr) * SF + fk];
        f16x8 b1 = *(const f16x8*)&Xt[(64 + 16 * j + fr) * SF + 32 + fk];
        f32x4 acc = {0.f, 0.f, 0.f, 0.f};
        acc = __builtin_amdgcn_mfma_f32_16x16x32_f16(pa0, b0, acc, 0, 0, 0);
        acc = __builtin_amdgcn_mfma_f32_16x16x32_f16(pa1, b1, acc, 0, 0, 0);
        const int dk = 16 * j + fr;
#pragma unroll
        for (int r = 0; r < 4; ++r) {
            const int t = 16 * w + er + r;
            Zg[slot + t * 64 + dk] = (f16)(el[t] * (float)Ql[t * SF + dk] - acc[r]);
        }
    }
#pragma unroll
    for (int j = 0; j < 4; ++j) {
        f16x8 b0 = *(const f16x8*)&Xt[(16 * j + fr) * SF + fk];
        f16x8 b1 = *(const f16x8*)&Xt[(16 * j + fr) * SF + 32 + fk];
        f32x4 acc = {0.f, 0.f, 0.f, 0.f};
        acc = __builtin_amdgcn_mfma_f32_16x16x32_f16(ka0, b0, acc, 0, 0, 0);
        acc = __builtin_amdgcn_mfma_f32_16x16x32_f16(ka1, b1, acc, 0, 0, 0);
        const int dv = 16 * j + fr;
#pragma unroll
        for (int r = 0; r < 4; ++r) {
            const int dk = 16 * w + er + r;
            Hg[slot + dk * 64 + dv] = (f16)acc[r];
        }
    }
    const float e63v = el[63];
#pragma unroll
    for (int j = 0; j < 4; ++j) {
        f16x8 b0 = *(const f16x8*)&Xt[(64 + 16 * j + fr) * SF + fk];
        f16x8 b1 = *(const f16x8*)&Xt[(64 + 16 * j + fr) * SF + 32 + fk];
        f32x4 acc = {0.f, 0.f, 0.f, 0.f};
        acc = __builtin_amdgcn_mfma_f32_16x16x32_f16(ka0, b0, acc, 0, 0, 0);
        acc = __builtin_amdgcn_mfma_f32_16x16x32_f16(ka1, b1, acc, 0, 0, 0);
        const int dk2 = 16 * j + fr;
#pragma unroll
        for (int r = 0; r < 4; ++r) {
            const int dk = 16 * w + er + r;
            Gg[slot + dk * 64 + dk2] = (f16)(((dk == dk2) ? e63v : 0.f) - acc[r]);
        }
    }
}

// ---------------------------------------------------------------------------
// Delta scan: S' = G@S + H only. Block = (seq, head). (unchanged)
// ---------------------------------------------------------------------------
__global__ __launch_bounds__(256) void delta_scan(
        const int* __restrict__ cu, const f16* __restrict__ Gg,
        const f16* __restrict__ Hg, f16* __restrict__ Sc) {
    const int b = blockIdx.x >> 4, h = blockIdx.x & 15;
    const int tid = threadIdx.x;
    const int lane = tid & 63, w = tid >> 6;
    const int fr = lane & 15;
    const int fk = (lane >> 4) * 8;
    const int er = (lane >> 4) * 4;

    __shared__ __align__(16) f16 Sl[64 * SF];   // S^T [dv][dk]
    for (int i = tid; i < 64 * SF; i += 256) Sl[i] = (f16)0.f;

    int cs = 0;
    for (int i = 0; i < b; ++i) cs += ((cu[i + 1] - cu[i]) + 63) >> 6;
    const int t0 = cu[b], t1 = cu[b + 1];
    const int nb = (t1 - t0 + 63) >> 6;

    for (int ci = 0; ci < nb; ++ci) {
        const size_t slot = (size_t)((cs + ci) * 16 + h) * 4096;
        __syncthreads();  // Sl stable (init or prev S-write)

        {
            const int r = tid >> 2;
            const int c0 = (tid & 3) * 16;
            uint4 s0 = *(const uint4*)&Sl[r * SF + c0];
            uint4 s1 = *(const uint4*)&Sl[r * SF + c0 + 8];
            *(uint4*)&Sc[slot + r * 64 + c0] = s0;
            *(uint4*)&Sc[slot + r * 64 + c0 + 8] = s1;
        }

        f16x8 ga0 = *(const f16x8*)&Gg[slot + (16 * w + fr) * 64 + fk];
        f16x8 ga1 = *(const f16x8*)&Gg[slot + (16 * w + fr) * 64 + 32 + fk];
        f16x8 sb[4][2];
        f32x4 acc[4];
#pragma unroll
        for (int j = 0; j < 4; ++j) {
            sb[j][0] = *(const f16x8*)&Sl[(16 * j + fr) * SF + fk];
            sb[j][1] = *(const f16x8*)&Sl[(16 * j + fr) * SF + 32 + fk];
            const int dv = 16 * j + fr;
#pragma unroll
            for (int r = 0; r < 4; ++r)
                acc[j][r] = (float)Hg[slot + (16 * w + er + r) * 64 + dv];
        }
        __syncthreads();  // all Sl reads done before overwrite
#pragma unroll
        for (int j = 0; j < 4; ++j) {
            acc[j] = __builtin_amdgcn_mfma_f32_16x16x32_f16(ga0, sb[j][0], acc[j], 0, 0, 0);
            acc[j] = __builtin_amdgcn_mfma_f32_16x16x32_f16(ga1, sb[j][1], acc[j], 0, 0, 0);
            const int dv = 16 * j + fr;
#pragma unroll
            for (int r = 0; r < 4; ++r)
                Sl[dv * SF + 16 * w + er + r] = (f16)acc[j][r];  // S'^T
        }
    }
}

// ---------------------------------------------------------------------------
// Delta out: O = ob + Z@Sc, fused gated RMSNorm -> obf. (unchanged)
// ---------------------------------------------------------------------------
__global__ __launch_bounds__(256) void delta_out(
        const int* __restrict__ cu, const f16* __restrict__ Zg,
        const f16* __restrict__ Sc, const float* __restrict__ ob,
        const f16* __restrict__ mixed3, const float* __restrict__ nw,
        f16* __restrict__ obf) {
    const int c = blockIdx.x >> 4;
    const int h = blockIdx.x & 15;
    int b = -1, base = 0, t1 = 0, cs = 0;
    for (int i = 0; i < NSEQ; ++i) {
        int len = cu[i + 1] - cu[i];
        int nbc = (len + 63) >> 6;
        if (b < 0) {
            if (c < cs + nbc) { b = i; base = cu[i] + (c - cs) * 64; t1 = cu[i + 1]; }
            else cs += nbc;
        }
    }
    if (b < 0) return;
    const size_t slot = (size_t)blockIdx.x * 4096;

    const int tid = threadIdx.x;
    const int lane = tid & 63, w = tid >> 6;
    const int fr = lane & 15;
    const int fk = (lane >> 4) * 8;
    const int er = (lane >> 4) * 4;

    f16x8 za0 = *(const f16x8*)&Zg[slot + (16 * w + fr) * 64 + fk];
    f16x8 za1 = *(const f16x8*)&Zg[slot + (16 * w + fr) * 64 + 32 + fk];

    float oacc[4][4];
#pragma unroll
    for (int j = 0; j < 4; ++j) {
        f16x8 b0 = *(const f16x8*)&Sc[slot + (16 * j + fr) * 64 + fk];
        f16x8 b1 = *(const f16x8*)&Sc[slot + (16 * j + fr) * 64 + 32 + fk];
        f32x4 acc = {0.f, 0.f, 0.f, 0.f};
        acc = __builtin_amdgcn_mfma_f32_16x16x32_f16(za0, b0, acc, 0, 0, 0);
        acc = __builtin_amdgcn_mfma_f32_16x16x32_f16(za1, b1, acc, 0, 0, 0);
        const int dv = 16 * j + fr;
#pragma unroll
        for (int r = 0; r < 4; ++r) {
            const int tau = base + 16 * w + er + r;
            oacc[j][r] = (tau < t1)
                ? ob[(size_t)tau * VAL_DIM + h * 64 + dv] + acc[r] : 0.f;
        }
    }
    float ss[4];
#pragma unroll
    for (int r = 0; r < 4; ++r) {
        ss[r] = oacc[0][r] * oacc[0][r] + oacc[1][r] * oacc[1][r]
              + oacc[2][r] * oacc[2][r] + oacc[3][r] * oacc[3][r];
#pragma unroll
        for (int m = 1; m < 16; m <<= 1) ss[r] += __shfl_xor(ss[r], m);
    }
#pragma unroll
    for (int r = 0; r < 4; ++r) {
        const int tau = base + 16 * w + er + r;
        if (tau < t1) {
            const float rms = rsqrtf(ss[r] * (1.f / 64.f) + 1e-6f);
#pragma unroll
            for (int j = 0; j < 4; ++j) {
                const int col = 16 * j + fr;
                const float z = (float)mixed3[(size_t)tau * NMIX + 2048 + h * 64 + col];
                const float sz = z / (1.f + expf(-z));
                obf[(size_t)tau * VAL_DIM + h * 64 + col] =
                    (f16)(oacc[j][r] * rms * nw[col] * sz);
            }
        }
    }
}

// ---------------------------------------------------------------------------
extern "C" void kernel_launch(void* const* d_in, const int* in_sizes, int n_in,
                              void* d_out, int out_size, void* d_ws, size_t ws_size,
                              hipStream_t stream) {
    const float* H    = (const float*)d_in[0];
    const float* Wqkv = (const float*)d_in[1];
    const float* Wz   = (const float*)d_in[2];
    const float* Wb   = (const float*)d_in[3];
    const float* Wa   = (const float*)d_in[4];
    const float* cwt  = (const float*)d_in[5];
    const float* dtb  = (const float*)d_in[6];
    const float* Alog = (const float*)d_in[7];
    const float* nw   = (const float*)d_in[8];
    const float* Wout = (const float*)d_in[9];
    const int*   cu   = (const int*)d_in[10];
    float* out = (float*)d_out;

    // --- Workspace (no aliasing; ws_size ~268 MB) ---
    f16* mixed3 = (f16*)d_ws;                              // 1536*3072 f16 (qkv | z)
    float* obuf  = (float*)(mixed3 + (size_t)TOTAL * NMIX);// 1536*1024 f32
    float* lgbuf = obuf + (size_t)TOTAL * VAL_DIM;         // 1536*16
    float* bbuf  = lgbuf + (size_t)TOTAL * HV;             // 1536*16
    f16* qbuf  = (f16*)(bbuf + (size_t)TOTAL * HV);        // 1536*512
    f16* kbuf  = qbuf + (size_t)TOTAL * KEY_DIM;           // 1536*512
    f16* vbuf  = kbuf + (size_t)TOTAL * KEY_DIM;           // 1536*1024
    f16* obf   = vbuf + (size_t)TOTAL * VAL_DIM;           // 1536*1024
    f16* Gg    = obf + (size_t)TOTAL * VAL_DIM;            // MAXCH*16*4096
    f16* Hg    = Gg + (size_t)MAXCH * 16 * 4096;
    f16* Zg    = Hg + (size_t)MAXCH * 16 * 4096;
    f16* Scg   = Zg + (size_t)MAXCH * 16 * 4096;           // entering states

    // 1) mixed3 = H @ [Wqkv;Wz]^T (fp32 in, f16 out; conversion in staging)
    gemm_qkvz<<<dim3(NMIX / 128, TOTAL / 128), 256, 0, stream>>>(
        H, Wqkv, Wz, mixed3, TOTAL, NMIX, HIDDEN);
    // 2) conv+silu+l2norm -> q,k,v (f16)  AND  beta / log-gamma (merged)
    conv_proj<<<TOTAL, 256, 0, stream>>>(mixed3, cwt, cu, H, Wb, Wa, dtb, Alog,
                                         qbuf, kbuf, vbuf, bbuf, lgbuf);
    // 3) delta phase 1 (chunk-parallel, MFMA)
    delta_phase1<<<MAXCH * 16, 256, 0, stream>>>(qbuf, kbuf, vbuf, lgbuf, bbuf,
                                                 cu, obuf, Gg, Hg, Zg);
    // 4) delta scan (serial part only): Sc per chunk
    delta_scan<<<NSEQ * HV, 256, 0, stream>>>(cu, Gg, Hg, Scg);
    // 5) delta out (parallel): O = ob + Z@Sc, fused gated RMSNorm -> obf
    delta_out<<<MAXCH * 16, 256, 0, stream>>>(cu, Zg, Scg, obuf, mixed3, nw, obf);
    // 6) out = obf @ Wout^T -> fp32 d_out (Wout converted in staging)
    gemm_out<<<dim3(HIDDEN / 128, TOTAL / 128), 256, 0, stream>>>(
        obf, Wout, out, TOTAL, HIDDEN, VAL_DIM);
}

// Round 19
// 204.602 us; speedup vs baseline: 1.2798x; 1.2798x over previous
//
#include <hip/hip_runtime.h>
#include <hip/hip_bf16.h>
#include <cstddef>

// Problem constants (fixed by setup_inputs)
#define TOTAL   1536
#define HIDDEN  1024
#define HK      8
#define HV      16
#define DK      64
#define DV      64
#define KSZ     4
#define KEY_DIM 512
#define VAL_DIM 1024
#define CONV_DIM 2048
#define NSEQ    4
#define MAXCH   27    // max total chunks
#define NMIX    3072  // merged qkv+z output width

typedef _Float16 f16;
typedef __attribute__((ext_vector_type(8))) _Float16 f16x8;
typedef __attribute__((ext_vector_type(4))) _Float16 f16x4;
typedef __attribute__((ext_vector_type(4))) float f32x4;

__device__ __forceinline__ void cstore(float* C, size_t idx, float v) { C[idx] = v; }
__device__ __forceinline__ void cstore(f16* C, size_t idx, float v) { C[idx] = (f16)v; }

// ---------------------------------------------------------------------------
// fp32 -> f16 pack, all four tensors in one launch (dst regions contiguous).
// ---------------------------------------------------------------------------
__global__ __launch_bounds__(256) void to_f16_all(const float* __restrict__ s0,
                                                  const float* __restrict__ s1,
                                                  const float* __restrict__ s2,
                                                  const float* __restrict__ s3,
                                                  f16* __restrict__ dst) {
    const int b = blockIdx.x;
    const float* src; int sb;
    if (b < 1536)      { src = s0; sb = 0; }
    else if (b < 3584) { src = s1; sb = 1536; }
    else if (b < 4608) { src = s2; sb = 3584; }
    else               { src = s3; sb = 4608; }
    const int local = (b - sb) * 1024 + threadIdx.x * 4;
    const int goff  = b * 1024 + threadIdx.x * 4;
    float4 v = *(const float4*)(src + local);
    f16x4 o = {(f16)v.x, (f16)v.y, (f16)v.z, (f16)v.w};
    *(f16x4*)(dst + goff) = o;
}

// ---------------------------------------------------------------------------
// MFMA GEMM: C[M,N] = A[M,K] @ B[N,K]^T.  A,B f16; C fp32 or f16.
// ---------------------------------------------------------------------------
#define LDK 72
template <typename TC>
__global__ __launch_bounds__(256) void gemm_mfma(const f16* __restrict__ A,
                                                 const f16* __restrict__ B,
                                                 TC* __restrict__ C,
                                                 int M, int N, int K) {
    __shared__ __align__(16) f16 As[128 * LDK];
    __shared__ __align__(16) f16 Bs[128 * LDK];
    const int tid = threadIdx.x;
    const int m0 = blockIdx.y * 128, n0 = blockIdx.x * 128;
    const int lane = tid & 63, w = tid >> 6;
    const int wm = (w >> 1) * 64, wn = (w & 1) * 64;
    const int fr = lane & 15;
    const int fk = (lane >> 4) * 8;
    const int sr = tid >> 1;
    const int sc = (tid & 1) * 32;

    f32x4 acc[4][4];
#pragma unroll
    for (int i = 0; i < 4; ++i)
#pragma unroll
        for (int j = 0; j < 4; ++j) acc[i][j] = (f32x4){0.f, 0.f, 0.f, 0.f};

    for (int kk = 0; kk < K; kk += 64) {
        const f16* ga = A + (size_t)(m0 + sr) * K + kk + sc;
        const f16* gb = B + (size_t)(n0 + sr) * K + kk + sc;
        uint4 a0 = *(const uint4*)(ga + 0);
        uint4 a1 = *(const uint4*)(ga + 8);
        uint4 a2 = *(const uint4*)(ga + 16);
        uint4 a3 = *(const uint4*)(ga + 24);
        uint4 b0 = *(const uint4*)(gb + 0);
        uint4 b1 = *(const uint4*)(gb + 8);
        uint4 b2 = *(const uint4*)(gb + 16);
        uint4 b3 = *(const uint4*)(gb + 24);
        __syncthreads();
        *(uint4*)&As[sr * LDK + sc + 0]  = a0;
        *(uint4*)&As[sr * LDK + sc + 8]  = a1;
        *(uint4*)&As[sr * LDK + sc + 16] = a2;
        *(uint4*)&As[sr * LDK + sc + 24] = a3;
        *(uint4*)&Bs[sr * LDK + sc + 0]  = b0;
        *(uint4*)&Bs[sr * LDK + sc + 8]  = b1;
        *(uint4*)&Bs[sr * LDK + sc + 16] = b2;
        *(uint4*)&Bs[sr * LDK + sc + 24] = b3;
        __syncthreads();

#pragma unroll
        for (int k2 = 0; k2 < 64; k2 += 32) {
            f16x8 af[4], bfr[4];
#pragma unroll
            for (int i = 0; i < 4; ++i)
                af[i] = *(const f16x8*)&As[(wm + i * 16 + fr) * LDK + k2 + fk];
#pragma unroll
            for (int j = 0; j < 4; ++j)
                bfr[j] = *(const f16x8*)&Bs[(wn + j * 16 + fr) * LDK + k2 + fk];
#pragma unroll
            for (int i = 0; i < 4; ++i)
#pragma unroll
                for (int j = 0; j < 4; ++j)
                    acc[i][j] = __builtin_amdgcn_mfma_f32_16x16x32_f16(
                        af[i], bfr[j], acc[i][j], 0, 0, 0);
        }
    }

    const int er = (lane >> 4) * 4;
#pragma unroll
    for (int i = 0; i < 4; ++i)
#pragma unroll
        for (int j = 0; j < 4; ++j) {
            const int col = n0 + wn + j * 16 + fr;
#pragma unroll
            for (int r = 0; r < 4; ++r) {
                const int row = m0 + wm + i * 16 + er + r;
                cstore(C, (size_t)row * N + col, acc[i][j][r]);
            }
        }
}

// ---------------------------------------------------------------------------
// Merged conv+proj. Block per token.
// Proj: wave-per-output (coalesced weight reads, shfl reduce).
// Conv: y in registers; per-head L2 sums via 16-lane shfl groups.
// ---------------------------------------------------------------------------
__global__ __launch_bounds__(256) void conv_proj(const f16* __restrict__ mixed3,
                                                 const float* __restrict__ cw,
                                                 const int* __restrict__ cu,
                                                 const float* __restrict__ H,
                                                 const float* __restrict__ Wb,
                                                 const float* __restrict__ Wa,
                                                 const float* __restrict__ dtb,
                                                 const float* __restrict__ Alog,
                                                 f16* __restrict__ qb,
                                                 f16* __restrict__ kb,
                                                 f16* __restrict__ vb,
                                                 float* __restrict__ betab,
                                                 float* __restrict__ lgb) {
    const int tok = blockIdx.x;
    const int tid = threadIdx.x;
    const int lane = tid & 63, w = tid >> 6;
    __shared__ float scale[16];

    int b = 0;
    for (int i = 1; i < NSEQ; ++i)
        if (tok >= cu[i]) b = i;
    const int pos = tok - cu[b];

    // ---- proj: wave w handles outputs o = it*4 + w, coalesced reads ----
#pragma unroll
    for (int it = 0; it < 8; ++it) {
        const int o = it * 4 + w;
        const float* wrow = (o < 16) ? (Wb + (size_t)o * HIDDEN)
                                     : (Wa + (size_t)(o - 16) * HIDDEN);
        float s = 0.f;
#pragma unroll
        for (int i = 0; i < 4; ++i) {
            float4 a = *(const float4*)&H[(size_t)tok * HIDDEN + i * 256 + lane * 4];
            float4 c = *(const float4*)&wrow[i * 256 + lane * 4];
            s += a.x * c.x + a.y * c.y + a.z * c.z + a.w * c.w;
        }
#pragma unroll
        for (int m = 1; m < 64; m <<= 1) s += __shfl_xor(s, m);
        if (lane == 0) {
            if (o < 16) {
                betab[tok * HV + o] = 1.f / (1.f + expf(-s));
            } else {
                const int hh = o - 16;
                float x = s + dtb[hh];
                float sp = (x > 20.f) ? x : log1pf(expf(x));
                lgb[tok * HV + hh] = -expf(Alog[hh]) * sp;
            }
        }
    }

    // ---- conv + silu, y in registers; it=0 pass also builds norm scales ----
    float4 yv[2];
#pragma unroll
    for (int it = 0; it < 2; ++it) {
        const int c0 = (tid + it * 256) * 4;
        float wf[4][4];
#pragma unroll
        for (int r = 0; r < 4; ++r) {
            float4 t4 = *(const float4*)&cw[(c0 + r) * 4];
            wf[r][0] = t4.x; wf[r][1] = t4.y; wf[r][2] = t4.z; wf[r][3] = t4.w;
        }
        float4 acc = {0.f, 0.f, 0.f, 0.f};
#pragma unroll
        for (int j = 0; j < KSZ; ++j) {
            const int off = j - (KSZ - 1);
            if (pos + off >= 0) {
                f16x4 xh = *(const f16x4*)&mixed3[(size_t)(tok + off) * NMIX + c0];
                acc.x += wf[0][j] * (float)xh[0]; acc.y += wf[1][j] * (float)xh[1];
                acc.z += wf[2][j] * (float)xh[2]; acc.w += wf[3][j] * (float)xh[3];
            }
        }
        float4 y;
        y.x = acc.x / (1.f + expf(-acc.x));
        y.y = acc.y / (1.f + expf(-acc.y));
        y.z = acc.z / (1.f + expf(-acc.z));
        y.w = acc.w / (1.f + expf(-acc.w));
        yv[it] = y;
        if (it == 0) {
            // channels 0..1023: head = tid>>4; 16 consecutive lanes per head
            float p = y.x * y.x + y.y * y.y + y.z * y.z + y.w * y.w;
            p += __shfl_xor(p, 1);
            p += __shfl_xor(p, 2);
            p += __shfl_xor(p, 4);
            p += __shfl_xor(p, 8);
            if ((tid & 15) == 0) scale[tid >> 4] = rsqrtf(p + 1e-6f);
        }
    }
    __syncthreads();

    // ---- q/k/v writes (f16) ----
#pragma unroll
    for (int it = 0; it < 2; ++it) {
        const int c0 = (tid + it * 256) * 4;
        float4 y = yv[it];
        if (c0 < KEY_DIM) {
            const float f = scale[c0 >> 6] * 0.125f;
            f16x4 r = {(f16)(y.x * f), (f16)(y.y * f), (f16)(y.z * f), (f16)(y.w * f)};
            *(f16x4*)&qb[(size_t)tok * KEY_DIM + c0] = r;
        } else if (c0 < 2 * KEY_DIM) {
            const float s = scale[c0 >> 6];
            f16x4 r = {(f16)(y.x * s), (f16)(y.y * s), (f16)(y.z * s), (f16)(y.w * s)};
            *(f16x4*)&kb[(size_t)tok * KEY_DIM + (c0 - KEY_DIM)] = r;
        } else {
            f16x4 r = {(f16)y.x, (f16)y.y, (f16)y.z, (f16)y.w};
            *(f16x4*)&vb[(size_t)tok * VAL_DIM + (c0 - 2 * KEY_DIM)] = r;
        }
    }
}

// ---------------------------------------------------------------------------
// Delta phase 1, MFMA. Block = (chunk, head).
// ---------------------------------------------------------------------------
#define SF 72   // f16 MFMA-array row stride
#define SA 68   // Am fp32 row stride
__global__ __launch_bounds__(256) void delta_phase1(
        const f16* __restrict__ qb, const f16* __restrict__ kb,
        const f16* __restrict__ vb, const float* __restrict__ lgb,
        const float* __restrict__ betab, const int* __restrict__ cu,
        float* __restrict__ ob, f16* __restrict__ Gg,
        f16* __restrict__ Hg, f16* __restrict__ Zg) {
    const int c = blockIdx.x >> 4;
    const int h = blockIdx.x & 15;
    const int hk = h >> 1;
    int b = -1, base = 0, t1 = 0, cs = 0;
    for (int i = 0; i < NSEQ; ++i) {
        int len = cu[i + 1] - cu[i];
        int nb = (len + 63) >> 6;
        if (b < 0) {
            if (c < cs + nb) { b = i; base = cu[i] + (c - cs) * 64; t1 = cu[i + 1]; }
            else cs += nb;
        }
    }
    if (b < 0) return;
    const size_t slot = (size_t)blockIdx.x * 4096;

    const int tid = threadIdx.x;
    const int lane = tid & 63, w = tid >> 6;
    const int fr = lane & 15;
    const int fk = (lane >> 4) * 8;
    const int er = (lane >> 4) * 4;

    __shared__ __align__(16) f16 Kl[64 * SF];    // [t][d]
    __shared__ __align__(16) f16 Ql[64 * SF];    // [t][d]
    __shared__ __align__(16) f16 KTd[64 * SF];   // [dk][t], pre-scaled by dsc[t]
    __shared__ __align__(16) f16 Xt[128 * SF];   // [col][t]
    __shared__ __align__(16) float Am[64 * SA];  // A fp32; later Pl f16
    __shared__ float cl[64], el[64], bl[64], lgl[64], dscl[64];
    f16* Pl = (f16*)Am;

    const int tt = tid >> 2;
    const int tau0 = base + tt;
    const bool valid = tau0 < t1;
    const f16x4 zh4 = {(f16)0.f, (f16)0.f, (f16)0.f, (f16)0.f};
    f16x4 kv[4], qv[4], vv[4];
#pragma unroll
    for (int u4 = 0; u4 < 4; ++u4) {
        const int d = ((tid & 3) << 2) + u4 * 16;
        kv[u4] = valid ? *(const f16x4*)&kb[(size_t)tau0 * KEY_DIM + hk * 64 + d] : zh4;
        qv[u4] = valid ? *(const f16x4*)&qb[(size_t)tau0 * KEY_DIM + hk * 64 + d] : zh4;
        vv[u4] = valid ? *(const f16x4*)&vb[(size_t)tau0 * VAL_DIM + h * 64 + d] : zh4;
    }
    if (tid < 64) {
        const int ta = base + tid;
        const bool v2 = ta < t1;
        lgl[tid] = v2 ? lgb[ta * HV + h] : 0.f;
        bl[tid]  = v2 ? betab[ta * HV + h] : 0.f;
    }
    __syncthreads();

    if (w == 0) {
        float x = lgl[lane];
#pragma unroll
        for (int off = 1; off < 64; off <<= 1) {
            float y = __shfl_up(x, off);
            if (lane >= off) x += y;
        }
        cl[lane] = x;
        el[lane] = expf(x);
        float c63 = __shfl(x, 63);
        dscl[lane] = expf(c63 - x);
    }
    __syncthreads();

    {
        const float bt = bl[tt], bet = bt * el[tt], ds = dscl[tt];
#pragma unroll
        for (int u4 = 0; u4 < 4; ++u4) {
            const int d = ((tid & 3) << 2) + u4 * 16;
            *(f16x4*)&Kl[tt * SF + d] = kv[u4];
            *(f16x4*)&Ql[tt * SF + d] = qv[u4];
#pragma unroll
            for (int e = 0; e < 4; ++e) {
                const float kf = (float)kv[u4][e];
                const float vf = (float)vv[u4][e];
                KTd[(d + e) * SF + tt] = (f16)(kf * ds);
                Xt[(d + e) * SF + tt] = (f16)(bt * vf);
                Xt[(64 + d + e) * SF + tt] = (f16)(bet * kf);
            }
        }
    }
    __syncthreads();

    // A-gram MFMA + decay -> Am fp32
    {
        f16x8 a0 = *(const f16x8*)&Kl[(16 * w + fr) * SF + fk];
        f16x8 a1 = *(const f16x8*)&Kl[(16 * w + fr) * SF + 32 + fk];
#pragma unroll
        for (int j = 0; j < 4; ++j) {
            f16x8 b0 = *(const f16x8*)&Kl[(16 * j + fr) * SF + fk];
            f16x8 b1 = *(const f16x8*)&Kl[(16 * j + fr) * SF + 32 + fk];
            f32x4 acc = {0.f, 0.f, 0.f, 0.f};
            acc = __builtin_amdgcn_mfma_f32_16x16x32_f16(a0, b0, acc, 0, 0, 0);
            acc = __builtin_amdgcn_mfma_f32_16x16x32_f16(a1, b1, acc, 0, 0, 0);
            const int s = 16 * j + fr;
#pragma unroll
            for (int r = 0; r < 4; ++r) {
                const int t = 16 * w + er + r;
                Am[t * SA + s] = (s < t) ? bl[t] * expf(cl[t] - cl[s]) * acc[r] : 0.f;
            }
        }
    }
    __syncthreads();

    // blocked fwd substitution on Xt (f16 storage, fp32 math)
#pragma unroll
    for (int ib = 0; ib < 4; ++ib) {
        if (tid < 128) {
            float xr[16];
#pragma unroll
            for (int i = 0; i < 16; ++i) {
                const int t = ib * 16 + i;
                float acc = (float)Xt[tid * SF + t];
#pragma unroll
                for (int s = 0; s < 16; ++s)
                    if (s < i) acc -= Am[t * SA + ib * 16 + s] * xr[s];
                xr[i] = acc;
                Xt[tid * SF + t] = (f16)acc;
            }
        }
        __syncthreads();
        if (ib < 3) {
            const int j = tid & 127;
            const int rh = tid >> 7;
            float us[16];
#pragma unroll
            for (int s = 0; s < 16; ++s) us[s] = (float)Xt[j * SF + ib * 16 + s];
            for (int r = (ib + 1) * 16 + rh; r < 64; r += 2) {
                float acc = (float)Xt[j * SF + r];
#pragma unroll
                for (int s = 0; s < 16; ++s)
                    acc -= Am[r * SA + ib * 16 + s] * us[s];
                Xt[j * SF + r] = (f16)acc;
            }
            __syncthreads();
        }
    }

    // P-gram MFMA -> Pl f16 (Am region; Am dead)
    {
        f16x8 a0 = *(const f16x8*)&Ql[(16 * w + fr) * SF + fk];
        f16x8 a1 = *(const f16x8*)&Ql[(16 * w + fr) * SF + 32 + fk];
        float pv[4][4];
#pragma unroll
        for (int j = 0; j < 4; ++j) {
            f16x8 b0 = *(const f16x8*)&Kl[(16 * j + fr) * SF + fk];
            f16x8 b1 = *(const f16x8*)&Kl[(16 * j + fr) * SF + 32 + fk];
            f32x4 acc = {0.f, 0.f, 0.f, 0.f};
            acc = __builtin_amdgcn_mfma_f32_16x16x32_f16(a0, b0, acc, 0, 0, 0);
            acc = __builtin_amdgcn_mfma_f32_16x16x32_f16(a1, b1, acc, 0, 0, 0);
            const int s = 16 * j + fr;
#pragma unroll
            for (int r = 0; r < 4; ++r) {
                const int t = 16 * w + er + r;
                pv[j][r] = (s <= t) ? expf(cl[t] - cl[s]) * acc[r] : 0.f;
            }
        }
#pragma unroll
        for (int j = 0; j < 4; ++j) {
            const int s = 16 * j + fr;
#pragma unroll
            for (int r = 0; r < 4; ++r)
                Pl[(16 * w + er + r) * SF + s] = (f16)pv[j][r];
        }
    }
    __syncthreads();

    // output MFMAs
    f16x8 pa0 = *(const f16x8*)&Pl[(16 * w + fr) * SF + fk];
    f16x8 pa1 = *(const f16x8*)&Pl[(16 * w + fr) * SF + 32 + fk];
    f16x8 ka0 = *(const f16x8*)&KTd[(16 * w + fr) * SF + fk];
    f16x8 ka1 = *(const f16x8*)&KTd[(16 * w + fr) * SF + 32 + fk];

#pragma unroll
    for (int j = 0; j < 4; ++j) {
        f16x8 b0 = *(const f16x8*)&Xt[(16 * j + fr) * SF + fk];
        f16x8 b1 = *(const f16x8*)&Xt[(16 * j + fr) * SF + 32 + fk];
        f32x4 acc = {0.f, 0.f, 0.f, 0.f};
        acc = __builtin_amdgcn_mfma_f32_16x16x32_f16(pa0, b0, acc, 0, 0, 0);
        acc = __builtin_amdgcn_mfma_f32_16x16x32_f16(pa1, b1, acc, 0, 0, 0);
        const int dv = 16 * j + fr;
#pragma unroll
        for (int r = 0; r < 4; ++r) {
            const int tau = base + 16 * w + er + r;
            if (tau < t1)
                ob[(size_t)tau * VAL_DIM + h * 64 + dv] = acc[r];
        }
    }
#pragma unroll
    for (int j = 0; j < 4; ++j) {
        f16x8 b0 = *(const f16x8*)&Xt[(64 + 16 * j + fr) * SF + fk];
        f16x8 b1 = *(const f16x8*)&Xt[(64 + 16 * j + fr) * SF + 32 + fk];
        f32x4 acc = {0.f, 0.f, 0.f, 0.f};
        acc = __builtin_amdgcn_mfma_f32_16x16x32_f16(pa0, b0, acc, 0, 0, 0);
        acc = __builtin_amdgcn_mfma_f32_16x16x32_f16(pa1, b1, acc, 0, 0, 0);
        const int dk = 16 * j + fr;
#pragma unroll
        for (int r = 0; r < 4; ++r) {
            const int t = 16 * w + er + r;
            Zg[slot + t * 64 + dk] = (f16)(el[t] * (float)Ql[t * SF + dk] - acc[r]);
        }
    }
#pragma unroll
    for (int j = 0; j < 4; ++j) {
        f16x8 b0 = *(const f16x8*)&Xt[(16 * j + fr) * SF + fk];
        f16x8 b1 = *(const f16x8*)&Xt[(16 * j + fr) * SF + 32 + fk];
        f32x4 acc = {0.f, 0.f, 0.f, 0.f};
        acc = __builtin_amdgcn_mfma_f32_16x16x32_f16(ka0, b0, acc, 0, 0, 0);
        acc = __builtin_amdgcn_mfma_f32_16x16x32_f16(ka1, b1, acc, 0, 0, 0);
        const int dv = 16 * j + fr;
#pragma unroll
        for (int r = 0; r < 4; ++r) {
            const int dk = 16 * w + er + r;
            Hg[slot + dk * 64 + dv] = (f16)acc[r];
        }
    }
    const float e63v = el[63];
#pragma unroll
    for (int j = 0; j < 4; ++j) {
        f16x8 b0 = *(const f16x8*)&Xt[(64 + 16 * j + fr) * SF + fk];
        f16x8 b1 = *(const f16x8*)&Xt[(64 + 16 * j + fr) * SF + 32 + fk];
        f32x4 acc = {0.f, 0.f, 0.f, 0.f};
        acc = __builtin_amdgcn_mfma_f32_16x16x32_f16(ka0, b0, acc, 0, 0, 0);
        acc = __builtin_amdgcn_mfma_f32_16x16x32_f16(ka1, b1, acc, 0, 0, 0);
        const int dk2 = 16 * j + fr;
#pragma unroll
        for (int r = 0; r < 4; ++r) {
            const int dk = 16 * w + er + r;
            Gg[slot + dk * 64 + dk2] = (f16)(((dk == dk2) ? e63v : 0.f) - acc[r]);
        }
    }
}

// ---------------------------------------------------------------------------
// Delta scan: S' = G@S + H only. Block = (seq, head).
// ---------------------------------------------------------------------------
__global__ __launch_bounds__(256) void delta_scan(
        const int* __restrict__ cu, const f16* __restrict__ Gg,
        const f16* __restrict__ Hg, f16* __restrict__ Sc) {
    const int b = blockIdx.x >> 4, h = blockIdx.x & 15;
    const int tid = threadIdx.x;
    const int lane = tid & 63, w = tid >> 6;
    const int fr = lane & 15;
    const int fk = (lane >> 4) * 8;
    const int er = (lane >> 4) * 4;

    __shared__ __align__(16) f16 Sl[64 * SF];   // S^T [dv][dk]
    for (int i = tid; i < 64 * SF; i += 256) Sl[i] = (f16)0.f;

    int cs = 0;
    for (int i = 0; i < b; ++i) cs += ((cu[i + 1] - cu[i]) + 63) >> 6;
    const int t0 = cu[b], t1 = cu[b + 1];
    const int nb = (t1 - t0 + 63) >> 6;

    for (int ci = 0; ci < nb; ++ci) {
        const size_t slot = (size_t)((cs + ci) * 16 + h) * 4096;
        __syncthreads();  // Sl stable (init or prev S-write)

        {
            const int r = tid >> 2;
            const int c0 = (tid & 3) * 16;
            uint4 s0 = *(const uint4*)&Sl[r * SF + c0];
            uint4 s1 = *(const uint4*)&Sl[r * SF + c0 + 8];
            *(uint4*)&Sc[slot + r * 64 + c0] = s0;
            *(uint4*)&Sc[slot + r * 64 + c0 + 8] = s1;
        }

        f16x8 ga0 = *(const f16x8*)&Gg[slot + (16 * w + fr) * 64 + fk];
        f16x8 ga1 = *(const f16x8*)&Gg[slot + (16 * w + fr) * 64 + 32 + fk];
        f16x8 sb[4][2];
        f32x4 acc[4];
#pragma unroll
        for (int j = 0; j < 4; ++j) {
            sb[j][0] = *(const f16x8*)&Sl[(16 * j + fr) * SF + fk];
            sb[j][1] = *(const f16x8*)&Sl[(16 * j + fr) * SF + 32 + fk];
            const int dv = 16 * j + fr;
#pragma unroll
            for (int r = 0; r < 4; ++r)
                acc[j][r] = (float)Hg[slot + (16 * w + er + r) * 64 + dv];
        }
        __syncthreads();  // all Sl reads done before overwrite
#pragma unroll
        for (int j = 0; j < 4; ++j) {
            acc[j] = __builtin_amdgcn_mfma_f32_16x16x32_f16(ga0, sb[j][0], acc[j], 0, 0, 0);
            acc[j] = __builtin_amdgcn_mfma_f32_16x16x32_f16(ga1, sb[j][1], acc[j], 0, 0, 0);
            const int dv = 16 * j + fr;
#pragma unroll
            for (int r = 0; r < 4; ++r)
                Sl[dv * SF + 16 * w + er + r] = (f16)acc[j][r];  // S'^T
        }
    }
}

// ---------------------------------------------------------------------------
// Delta out: O = ob + Z@Sc, fused gated RMSNorm -> obf.
// ---------------------------------------------------------------------------
__global__ __launch_bounds__(256) void delta_out(
        const int* __restrict__ cu, const f16* __restrict__ Zg,
        const f16* __restrict__ Sc, const float* __restrict__ ob,
        const f16* __restrict__ mixed3, const float* __restrict__ nw,
        f16* __restrict__ obf) {
    const int c = blockIdx.x >> 4;
    const int h = blockIdx.x & 15;
    int b = -1, base = 0, t1 = 0, cs = 0;
    for (int i = 0; i < NSEQ; ++i) {
        int len = cu[i + 1] - cu[i];
        int nbc = (len + 63) >> 6;
        if (b < 0) {
            if (c < cs + nbc) { b = i; base = cu[i] + (c - cs) * 64; t1 = cu[i + 1]; }
            else cs += nbc;
        }
    }
    if (b < 0) return;
    const size_t slot = (size_t)blockIdx.x * 4096;

    const int tid = threadIdx.x;
    const int lane = tid & 63, w = tid >> 6;
    const int fr = lane & 15;
    const int fk = (lane >> 4) * 8;
    const int er = (lane >> 4) * 4;

    f16x8 za0 = *(const f16x8*)&Zg[slot + (16 * w + fr) * 64 + fk];
    f16x8 za1 = *(const f16x8*)&Zg[slot + (16 * w + fr) * 64 + 32 + fk];

    float oacc[4][4];
#pragma unroll
    for (int j = 0; j < 4; ++j) {
        f16x8 b0 = *(const f16x8*)&Sc[slot + (16 * j + fr) * 64 + fk];
        f16x8 b1 = *(const f16x8*)&Sc[slot + (16 * j + fr) * 64 + 32 + fk];
        f32x4 acc = {0.f, 0.f, 0.f, 0.f};
        acc = __builtin_amdgcn_mfma_f32_16x16x32_f16(za0, b0, acc, 0, 0, 0);
        acc = __builtin_amdgcn_mfma_f32_16x16x32_f16(za1, b1, acc, 0, 0, 0);
        const int dv = 16 * j + fr;
#pragma unroll
        for (int r = 0; r < 4; ++r) {
            const int tau = base + 16 * w + er + r;
            oacc[j][r] = (tau < t1)
                ? ob[(size_t)tau * VAL_DIM + h * 64 + dv] + acc[r] : 0.f;
        }
    }
    float ss[4];
#pragma unroll
    for (int r = 0; r < 4; ++r) {
        ss[r] = oacc[0][r] * oacc[0][r] + oacc[1][r] * oacc[1][r]
              + oacc[2][r] * oacc[2][r] + oacc[3][r] * oacc[3][r];
#pragma unroll
        for (int m = 1; m < 16; m <<= 1) ss[r] += __shfl_xor(ss[r], m);
    }
#pragma unroll
    for (int r = 0; r < 4; ++r) {
        const int tau = base + 16 * w + er + r;
        if (tau < t1) {
            const float rms = rsqrtf(ss[r] * (1.f / 64.f) + 1e-6f);
#pragma unroll
            for (int j = 0; j < 4; ++j) {
                const int col = 16 * j + fr;
                const float z = (float)mixed3[(size_t)tau * NMIX + 2048 + h * 64 + col];
                const float sz = z / (1.f + expf(-z));
                obf[(size_t)tau * VAL_DIM + h * 64 + col] =
                    (f16)(oacc[j][r] * rms * nw[col] * sz);
            }
        }
    }
}

// ---------------------------------------------------------------------------
extern "C" void kernel_launch(void* const* d_in, const int* in_sizes, int n_in,
                              void* d_out, int out_size, void* d_ws, size_t ws_size,
                              hipStream_t stream) {
    const float* H    = (const float*)d_in[0];
    const float* Wqkv = (const float*)d_in[1];
    const float* Wz   = (const float*)d_in[2];
    const float* Wb   = (const float*)d_in[3];
    const float* Wa   = (const float*)d_in[4];
    const float* cwt  = (const float*)d_in[5];
    const float* dtb  = (const float*)d_in[6];
    const float* Alog = (const float*)d_in[7];
    const float* nw   = (const float*)d_in[8];
    const float* Wout = (const float*)d_in[9];
    const int*   cu   = (const int*)d_in[10];
    float* out = (float*)d_out;

    // --- Workspace (no aliasing; ws_size ~268 MB) ---
    f16* mixed3 = (f16*)d_ws;                              // 1536*3072 f16 (qkv | z)
    float* obuf  = (float*)(mixed3 + (size_t)TOTAL * NMIX);// 1536*1024 f32
    float* lgbuf = obuf + (size_t)TOTAL * VAL_DIM;         // 1536*16
    float* bbuf  = lgbuf + (size_t)TOTAL * HV;             // 1536*16
    f16* Hb    = (f16*)(bbuf + (size_t)TOTAL * HV);        // 1536*1024
    f16* Wqkvb = Hb + (size_t)TOTAL * HIDDEN;              // 2048*1024
    f16* Wzb   = Wqkvb + (size_t)CONV_DIM * HIDDEN;        // 1024*1024 (contiguous)
    f16* Woutb = Wzb + (size_t)VAL_DIM * HIDDEN;           // 1024*1024
    f16* qbuf  = Woutb + (size_t)HIDDEN * VAL_DIM;         // 1536*512
    f16* kbuf  = qbuf + (size_t)TOTAL * KEY_DIM;           // 1536*512
    f16* vbuf  = kbuf + (size_t)TOTAL * KEY_DIM;           // 1536*1024
    f16* obf   = vbuf + (size_t)TOTAL * VAL_DIM;           // 1536*1024
    f16* Gg    = obf + (size_t)TOTAL * VAL_DIM;            // MAXCH*16*4096
    f16* Hg    = Gg + (size_t)MAXCH * 16 * 4096;
    f16* Zg    = Hg + (size_t)MAXCH * 16 * 4096;
    f16* Scg   = Zg + (size_t)MAXCH * 16 * 4096;           // entering states

    // 0) f16 conversions
    to_f16_all<<<5632, 256, 0, stream>>>(H, Wqkv, Wz, Wout, Hb);

    // 1) mixed3 = H @ [Wqkv;Wz]^T  (1536 x 3072) -> f16
    gemm_mfma<f16><<<dim3(NMIX / 128, TOTAL / 128), 256, 0, stream>>>(
        Hb, Wqkvb, mixed3, TOTAL, NMIX, HIDDEN);
    // 2) conv+silu+l2norm -> q,k,v (f16)  AND  beta / log-gamma (merged)
    conv_proj<<<TOTAL, 256, 0, stream>>>(mixed3, cwt, cu, H, Wb, Wa, dtb, Alog,
                                         qbuf, kbuf, vbuf, bbuf, lgbuf);
    // 3) delta phase 1 (chunk-parallel, MFMA)
    delta_phase1<<<MAXCH * 16, 256, 0, stream>>>(qbuf, kbuf, vbuf, lgbuf, bbuf,
                                                 cu, obuf, Gg, Hg, Zg);
    // 4) delta scan (serial part only): Sc per chunk
    delta_scan<<<NSEQ * HV, 256, 0, stream>>>(cu, Gg, Hg, Scg);
    // 5) delta out (parallel): O = ob + Z@Sc, fused gated RMSNorm -> obf
    delta_out<<<MAXCH * 16, 256, 0, stream>>>(cu, Zg, Scg, obuf, mixed3, nw, obf);
    // 6) out = obf @ W_out^T -> fp32 d_out
    gemm_mfma<float><<<dim3(HIDDEN / 128, TOTAL / 128), 256, 0, stream>>>(
        obf, Woutb, out, TOTAL, HIDDEN, VAL_DIM);
}

// Round 20
// 199.770 us; speedup vs baseline: 1.3108x; 1.0242x over previous
//
#include <hip/hip_runtime.h>
#include <hip/hip_bf16.h>
#include <cstddef>

// Problem constants (fixed by setup_inputs)
#define TOTAL   1536
#define HIDDEN  1024
#define HK      8
#define HV      16
#define DK      64
#define DV      64
#define KSZ     4
#define KEY_DIM 512
#define VAL_DIM 1024
#define CONV_DIM 2048
#define NSEQ    4
#define MAXCH   27    // max total chunks
#define NMIX    3072  // merged qkv+z output width

typedef _Float16 f16;
typedef __attribute__((ext_vector_type(8))) _Float16 f16x8;
typedef __attribute__((ext_vector_type(4))) _Float16 f16x4;
typedef __attribute__((ext_vector_type(4))) float f32x4;

__device__ __forceinline__ void cstore(float* C, size_t idx, float v) { C[idx] = v; }
__device__ __forceinline__ void cstore(f16* C, size_t idx, float v) { C[idx] = (f16)v; }

// ---------------------------------------------------------------------------
// fp32 -> f16 pack, all four tensors in one launch (dst regions contiguous).
// ---------------------------------------------------------------------------
__global__ __launch_bounds__(256) void to_f16_all(const float* __restrict__ s0,
                                                  const float* __restrict__ s1,
                                                  const float* __restrict__ s2,
                                                  const float* __restrict__ s3,
                                                  f16* __restrict__ dst) {
    const int b = blockIdx.x;
    const float* src; int sb;
    if (b < 1536)      { src = s0; sb = 0; }
    else if (b < 3584) { src = s1; sb = 1536; }
    else if (b < 4608) { src = s2; sb = 3584; }
    else               { src = s3; sb = 4608; }
    const int local = (b - sb) * 1024 + threadIdx.x * 4;
    const int goff  = b * 1024 + threadIdx.x * 4;
    float4 v = *(const float4*)(src + local);
    f16x4 o = {(f16)v.x, (f16)v.y, (f16)v.z, (f16)v.w};
    *(f16x4*)(dst + goff) = o;
}

// ---------------------------------------------------------------------------
// MFMA GEMM, double-buffered LDS: C[M,N] = A[M,K] @ B[N,K]^T. A,B f16.
// 128x128 tile, BK=64, 256 threads. 1 barrier / K-iteration; global-load
// latency of tile k+1 hides behind MFMAs on tile k (critical at 1 wave/SIMD).
// ---------------------------------------------------------------------------
#define LDK 72
template <typename TC>
__global__ __launch_bounds__(256) void gemm_mfma(const f16* __restrict__ A,
                                                 const f16* __restrict__ B,
                                                 TC* __restrict__ C,
                                                 int M, int N, int K) {
    __shared__ __align__(16) f16 As[2][128 * LDK];
    __shared__ __align__(16) f16 Bs[2][128 * LDK];
    const int tid = threadIdx.x;
    const int m0 = blockIdx.y * 128, n0 = blockIdx.x * 128;
    const int lane = tid & 63, w = tid >> 6;
    const int wm = (w >> 1) * 64, wn = (w & 1) * 64;
    const int fr = lane & 15;
    const int fk = (lane >> 4) * 8;
    const int sr = tid >> 1;
    const int sc = (tid & 1) * 32;

    f32x4 acc[4][4];
#pragma unroll
    for (int i = 0; i < 4; ++i)
#pragma unroll
        for (int j = 0; j < 4; ++j) acc[i][j] = (f32x4){0.f, 0.f, 0.f, 0.f};

    const f16* ga = A + (size_t)(m0 + sr) * K + sc;
    const f16* gb = B + (size_t)(n0 + sr) * K + sc;

    // preload tile 0
    {
        uint4 a0 = *(const uint4*)(ga + 0);
        uint4 a1 = *(const uint4*)(ga + 8);
        uint4 a2 = *(const uint4*)(ga + 16);
        uint4 a3 = *(const uint4*)(ga + 24);
        uint4 b0 = *(const uint4*)(gb + 0);
        uint4 b1 = *(const uint4*)(gb + 8);
        uint4 b2 = *(const uint4*)(gb + 16);
        uint4 b3 = *(const uint4*)(gb + 24);
        *(uint4*)&As[0][sr * LDK + sc + 0]  = a0;
        *(uint4*)&As[0][sr * LDK + sc + 8]  = a1;
        *(uint4*)&As[0][sr * LDK + sc + 16] = a2;
        *(uint4*)&As[0][sr * LDK + sc + 24] = a3;
        *(uint4*)&Bs[0][sr * LDK + sc + 0]  = b0;
        *(uint4*)&Bs[0][sr * LDK + sc + 8]  = b1;
        *(uint4*)&Bs[0][sr * LDK + sc + 16] = b2;
        *(uint4*)&Bs[0][sr * LDK + sc + 24] = b3;
    }
    __syncthreads();

    int cur = 0;
    for (int kk = 64; kk <= K; kk += 64) {
        const bool more = kk < K;
        uint4 a0, a1, a2, a3, b0, b1, b2, b3;
        if (more) {  // issue loads for next tile (latency hidden by MFMAs)
            a0 = *(const uint4*)(ga + kk + 0);
            a1 = *(const uint4*)(ga + kk + 8);
            a2 = *(const uint4*)(ga + kk + 16);
            a3 = *(const uint4*)(ga + kk + 24);
            b0 = *(const uint4*)(gb + kk + 0);
            b1 = *(const uint4*)(gb + kk + 8);
            b2 = *(const uint4*)(gb + kk + 16);
            b3 = *(const uint4*)(gb + kk + 24);
        }

        // compute on buffer `cur`
#pragma unroll
        for (int k2 = 0; k2 < 64; k2 += 32) {
            f16x8 af[4], bfr[4];
#pragma unroll
            for (int i = 0; i < 4; ++i)
                af[i] = *(const f16x8*)&As[cur][(wm + i * 16 + fr) * LDK + k2 + fk];
#pragma unroll
            for (int j = 0; j < 4; ++j)
                bfr[j] = *(const f16x8*)&Bs[cur][(wn + j * 16 + fr) * LDK + k2 + fk];
#pragma unroll
            for (int i = 0; i < 4; ++i)
#pragma unroll
                for (int j = 0; j < 4; ++j)
                    acc[i][j] = __builtin_amdgcn_mfma_f32_16x16x32_f16(
                        af[i], bfr[j], acc[i][j], 0, 0, 0);
        }

        if (more) {  // write next tile into the other buffer; single barrier
            const int nxt = cur ^ 1;
            *(uint4*)&As[nxt][sr * LDK + sc + 0]  = a0;
            *(uint4*)&As[nxt][sr * LDK + sc + 8]  = a1;
            *(uint4*)&As[nxt][sr * LDK + sc + 16] = a2;
            *(uint4*)&As[nxt][sr * LDK + sc + 24] = a3;
            *(uint4*)&Bs[nxt][sr * LDK + sc + 0]  = b0;
            *(uint4*)&Bs[nxt][sr * LDK + sc + 8]  = b1;
            *(uint4*)&Bs[nxt][sr * LDK + sc + 16] = b2;
            *(uint4*)&Bs[nxt][sr * LDK + sc + 24] = b3;
            __syncthreads();
            cur = nxt;
        }
    }

    const int er = (lane >> 4) * 4;
#pragma unroll
    for (int i = 0; i < 4; ++i)
#pragma unroll
        for (int j = 0; j < 4; ++j) {
            const int col = n0 + wn + j * 16 + fr;
#pragma unroll
            for (int r = 0; r < 4; ++r) {
                const int row = m0 + wm + i * 16 + er + r;
                cstore(C, (size_t)row * N + col, acc[i][j][r]);
            }
        }
}

// ---------------------------------------------------------------------------
// Merged conv+proj. Block per token. (unchanged R19)
// ---------------------------------------------------------------------------
__global__ __launch_bounds__(256) void conv_proj(const f16* __restrict__ mixed3,
                                                 const float* __restrict__ cw,
                                                 const int* __restrict__ cu,
                                                 const float* __restrict__ H,
                                                 const float* __restrict__ Wb,
                                                 const float* __restrict__ Wa,
                                                 const float* __restrict__ dtb,
                                                 const float* __restrict__ Alog,
                                                 f16* __restrict__ qb,
                                                 f16* __restrict__ kb,
                                                 f16* __restrict__ vb,
                                                 float* __restrict__ betab,
                                                 float* __restrict__ lgb) {
    const int tok = blockIdx.x;
    const int tid = threadIdx.x;
    const int lane = tid & 63, w = tid >> 6;
    __shared__ float scale[16];

    int b = 0;
    for (int i = 1; i < NSEQ; ++i)
        if (tok >= cu[i]) b = i;
    const int pos = tok - cu[b];

#pragma unroll
    for (int it = 0; it < 8; ++it) {
        const int o = it * 4 + w;
        const float* wrow = (o < 16) ? (Wb + (size_t)o * HIDDEN)
                                     : (Wa + (size_t)(o - 16) * HIDDEN);
        float s = 0.f;
#pragma unroll
        for (int i = 0; i < 4; ++i) {
            float4 a = *(const float4*)&H[(size_t)tok * HIDDEN + i * 256 + lane * 4];
            float4 c = *(const float4*)&wrow[i * 256 + lane * 4];
            s += a.x * c.x + a.y * c.y + a.z * c.z + a.w * c.w;
        }
#pragma unroll
        for (int m = 1; m < 64; m <<= 1) s += __shfl_xor(s, m);
        if (lane == 0) {
            if (o < 16) {
                betab[tok * HV + o] = 1.f / (1.f + expf(-s));
            } else {
                const int hh = o - 16;
                float x = s + dtb[hh];
                float sp = (x > 20.f) ? x : log1pf(expf(x));
                lgb[tok * HV + hh] = -expf(Alog[hh]) * sp;
            }
        }
    }

    float4 yv[2];
#pragma unroll
    for (int it = 0; it < 2; ++it) {
        const int c0 = (tid + it * 256) * 4;
        float wf[4][4];
#pragma unroll
        for (int r = 0; r < 4; ++r) {
            float4 t4 = *(const float4*)&cw[(c0 + r) * 4];
            wf[r][0] = t4.x; wf[r][1] = t4.y; wf[r][2] = t4.z; wf[r][3] = t4.w;
        }
        float4 acc = {0.f, 0.f, 0.f, 0.f};
#pragma unroll
        for (int j = 0; j < KSZ; ++j) {
            const int off = j - (KSZ - 1);
            if (pos + off >= 0) {
                f16x4 xh = *(const f16x4*)&mixed3[(size_t)(tok + off) * NMIX + c0];
                acc.x += wf[0][j] * (float)xh[0]; acc.y += wf[1][j] * (float)xh[1];
                acc.z += wf[2][j] * (float)xh[2]; acc.w += wf[3][j] * (float)xh[3];
            }
        }
        float4 y;
        y.x = acc.x / (1.f + expf(-acc.x));
        y.y = acc.y / (1.f + expf(-acc.y));
        y.z = acc.z / (1.f + expf(-acc.z));
        y.w = acc.w / (1.f + expf(-acc.w));
        yv[it] = y;
        if (it == 0) {
            float p = y.x * y.x + y.y * y.y + y.z * y.z + y.w * y.w;
            p += __shfl_xor(p, 1);
            p += __shfl_xor(p, 2);
            p += __shfl_xor(p, 4);
            p += __shfl_xor(p, 8);
            if ((tid & 15) == 0) scale[tid >> 4] = rsqrtf(p + 1e-6f);
        }
    }
    __syncthreads();

#pragma unroll
    for (int it = 0; it < 2; ++it) {
        const int c0 = (tid + it * 256) * 4;
        float4 y = yv[it];
        if (c0 < KEY_DIM) {
            const float f = scale[c0 >> 6] * 0.125f;
            f16x4 r = {(f16)(y.x * f), (f16)(y.y * f), (f16)(y.z * f), (f16)(y.w * f)};
            *(f16x4*)&qb[(size_t)tok * KEY_DIM + c0] = r;
        } else if (c0 < 2 * KEY_DIM) {
            const float s = scale[c0 >> 6];
            f16x4 r = {(f16)(y.x * s), (f16)(y.y * s), (f16)(y.z * s), (f16)(y.w * s)};
            *(f16x4*)&kb[(size_t)tok * KEY_DIM + (c0 - KEY_DIM)] = r;
        } else {
            f16x4 r = {(f16)y.x, (f16)y.y, (f16)y.z, (f16)y.w};
            *(f16x4*)&vb[(size_t)tok * VAL_DIM + (c0 - 2 * KEY_DIM)] = r;
        }
    }
}

// ---------------------------------------------------------------------------
// Delta phase 1, MFMA. Block = (chunk, head). (unchanged)
// ---------------------------------------------------------------------------
#define SF 72   // f16 MFMA-array row stride
#define SA 68   // Am fp32 row stride
__global__ __launch_bounds__(256) void delta_phase1(
        const f16* __restrict__ qb, const f16* __restrict__ kb,
        const f16* __restrict__ vb, const float* __restrict__ lgb,
        const float* __restrict__ betab, const int* __restrict__ cu,
        float* __restrict__ ob, f16* __restrict__ Gg,
        f16* __restrict__ Hg, f16* __restrict__ Zg) {
    const int c = blockIdx.x >> 4;
    const int h = blockIdx.x & 15;
    const int hk = h >> 1;
    int b = -1, base = 0, t1 = 0, cs = 0;
    for (int i = 0; i < NSEQ; ++i) {
        int len = cu[i + 1] - cu[i];
        int nb = (len + 63) >> 6;
        if (b < 0) {
            if (c < cs + nb) { b = i; base = cu[i] + (c - cs) * 64; t1 = cu[i + 1]; }
            else cs += nb;
        }
    }
    if (b < 0) return;
    const size_t slot = (size_t)blockIdx.x * 4096;

    const int tid = threadIdx.x;
    const int lane = tid & 63, w = tid >> 6;
    const int fr = lane & 15;
    const int fk = (lane >> 4) * 8;
    const int er = (lane >> 4) * 4;

    __shared__ __align__(16) f16 Kl[64 * SF];    // [t][d]
    __shared__ __align__(16) f16 Ql[64 * SF];    // [t][d]
    __shared__ __align__(16) f16 KTd[64 * SF];   // [dk][t], pre-scaled by dsc[t]
    __shared__ __align__(16) f16 Xt[128 * SF];   // [col][t]
    __shared__ __align__(16) float Am[64 * SA];  // A fp32; later Pl f16
    __shared__ float cl[64], el[64], bl[64], lgl[64], dscl[64];
    f16* Pl = (f16*)Am;

    const int tt = tid >> 2;
    const int tau0 = base + tt;
    const bool valid = tau0 < t1;
    const f16x4 zh4 = {(f16)0.f, (f16)0.f, (f16)0.f, (f16)0.f};
    f16x4 kv[4], qv[4], vv[4];
#pragma unroll
    for (int u4 = 0; u4 < 4; ++u4) {
        const int d = ((tid & 3) << 2) + u4 * 16;
        kv[u4] = valid ? *(const f16x4*)&kb[(size_t)tau0 * KEY_DIM + hk * 64 + d] : zh4;
        qv[u4] = valid ? *(const f16x4*)&qb[(size_t)tau0 * KEY_DIM + hk * 64 + d] : zh4;
        vv[u4] = valid ? *(const f16x4*)&vb[(size_t)tau0 * VAL_DIM + h * 64 + d] : zh4;
    }
    if (tid < 64) {
        const int ta = base + tid;
        const bool v2 = ta < t1;
        lgl[tid] = v2 ? lgb[ta * HV + h] : 0.f;
        bl[tid]  = v2 ? betab[ta * HV + h] : 0.f;
    }
    __syncthreads();

    if (w == 0) {
        float x = lgl[lane];
#pragma unroll
        for (int off = 1; off < 64; off <<= 1) {
            float y = __shfl_up(x, off);
            if (lane >= off) x += y;
        }
        cl[lane] = x;
        el[lane] = expf(x);
        float c63 = __shfl(x, 63);
        dscl[lane] = expf(c63 - x);
    }
    __syncthreads();

    {
        const float bt = bl[tt], bet = bt * el[tt], ds = dscl[tt];
#pragma unroll
        for (int u4 = 0; u4 < 4; ++u4) {
            const int d = ((tid & 3) << 2) + u4 * 16;
            *(f16x4*)&Kl[tt * SF + d] = kv[u4];
            *(f16x4*)&Ql[tt * SF + d] = qv[u4];
#pragma unroll
            for (int e = 0; e < 4; ++e) {
                const float kf = (float)kv[u4][e];
                const float vf = (float)vv[u4][e];
                KTd[(d + e) * SF + tt] = (f16)(kf * ds);
                Xt[(d + e) * SF + tt] = (f16)(bt * vf);
                Xt[(64 + d + e) * SF + tt] = (f16)(bet * kf);
            }
        }
    }
    __syncthreads();

    // A-gram MFMA + decay -> Am fp32
    {
        f16x8 a0 = *(const f16x8*)&Kl[(16 * w + fr) * SF + fk];
        f16x8 a1 = *(const f16x8*)&Kl[(16 * w + fr) * SF + 32 + fk];
#pragma unroll
        for (int j = 0; j < 4; ++j) {
            f16x8 b0 = *(const f16x8*)&Kl[(16 * j + fr) * SF + fk];
            f16x8 b1 = *(const f16x8*)&Kl[(16 * j + fr) * SF + 32 + fk];
            f32x4 acc = {0.f, 0.f, 0.f, 0.f};
            acc = __builtin_amdgcn_mfma_f32_16x16x32_f16(a0, b0, acc, 0, 0, 0);
            acc = __builtin_amdgcn_mfma_f32_16x16x32_f16(a1, b1, acc, 0, 0, 0);
            const int s = 16 * j + fr;
#pragma unroll
            for (int r = 0; r < 4; ++r) {
                const int t = 16 * w + er + r;
                Am[t * SA + s] = (s < t) ? bl[t] * expf(cl[t] - cl[s]) * acc[r] : 0.f;
            }
        }
    }
    __syncthreads();

    // blocked fwd substitution on Xt (f16 storage, fp32 math)
#pragma unroll
    for (int ib = 0; ib < 4; ++ib) {
        if (tid < 128) {
            float xr[16];
#pragma unroll
            for (int i = 0; i < 16; ++i) {
                const int t = ib * 16 + i;
                float acc = (float)Xt[tid * SF + t];
#pragma unroll
                for (int s = 0; s < 16; ++s)
                    if (s < i) acc -= Am[t * SA + ib * 16 + s] * xr[s];
                xr[i] = acc;
                Xt[tid * SF + t] = (f16)acc;
            }
        }
        __syncthreads();
        if (ib < 3) {
            const int j = tid & 127;
            const int rh = tid >> 7;
            float us[16];
#pragma unroll
            for (int s = 0; s < 16; ++s) us[s] = (float)Xt[j * SF + ib * 16 + s];
            for (int r = (ib + 1) * 16 + rh; r < 64; r += 2) {
                float acc = (float)Xt[j * SF + r];
#pragma unroll
                for (int s = 0; s < 16; ++s)
                    acc -= Am[r * SA + ib * 16 + s] * us[s];
                Xt[j * SF + r] = (f16)acc;
            }
            __syncthreads();
        }
    }

    // P-gram MFMA -> Pl f16 (Am region; Am dead)
    {
        f16x8 a0 = *(const f16x8*)&Ql[(16 * w + fr) * SF + fk];
        f16x8 a1 = *(const f16x8*)&Ql[(16 * w + fr) * SF + 32 + fk];
        float pv[4][4];
#pragma unroll
        for (int j = 0; j < 4; ++j) {
            f16x8 b0 = *(const f16x8*)&Kl[(16 * j + fr) * SF + fk];
            f16x8 b1 = *(const f16x8*)&Kl[(16 * j + fr) * SF + 32 + fk];
            f32x4 acc = {0.f, 0.f, 0.f, 0.f};
            acc = __builtin_amdgcn_mfma_f32_16x16x32_f16(a0, b0, acc, 0, 0, 0);
            acc = __builtin_amdgcn_mfma_f32_16x16x32_f16(a1, b1, acc, 0, 0, 0);
            const int s = 16 * j + fr;
#pragma unroll
            for (int r = 0; r < 4; ++r) {
                const int t = 16 * w + er + r;
                pv[j][r] = (s <= t) ? expf(cl[t] - cl[s]) * acc[r] : 0.f;
            }
        }
#pragma unroll
        for (int j = 0; j < 4; ++j) {
            const int s = 16 * j + fr;
#pragma unroll
            for (int r = 0; r < 4; ++r)
                Pl[(16 * w + er + r) * SF + s] = (f16)pv[j][r];
        }
    }
    __syncthreads();

    // output MFMAs
    f16x8 pa0 = *(const f16x8*)&Pl[(16 * w + fr) * SF + fk];
    f16x8 pa1 = *(const f16x8*)&Pl[(16 * w + fr) * SF + 32 + fk];
    f16x8 ka0 = *(const f16x8*)&KTd[(16 * w + fr) * SF + fk];
    f16x8 ka1 = *(const f16x8*)&KTd[(16 * w + fr) * SF + 32 + fk];

#pragma unroll
    for (int j = 0; j < 4; ++j) {
        f16x8 b0 = *(const f16x8*)&Xt[(16 * j + fr) * SF + fk];
        f16x8 b1 = *(const f16x8*)&Xt[(16 * j + fr) * SF + 32 + fk];
        f32x4 acc = {0.f, 0.f, 0.f, 0.f};
        acc = __builtin_amdgcn_mfma_f32_16x16x32_f16(pa0, b0, acc, 0, 0, 0);
        acc = __builtin_amdgcn_mfma_f32_16x16x32_f16(pa1, b1, acc, 0, 0, 0);
        const int dv = 16 * j + fr;
#pragma unroll
        for (int r = 0; r < 4; ++r) {
            const int tau = base + 16 * w + er + r;
            if (tau < t1)
                ob[(size_t)tau * VAL_DIM + h * 64 + dv] = acc[r];
        }
    }
#pragma unroll
    for (int j = 0; j < 4; ++j) {
        f16x8 b0 = *(const f16x8*)&Xt[(64 + 16 * j + fr) * SF + fk];
        f16x8 b1 = *(const f16x8*)&Xt[(64 + 16 * j + fr) * SF + 32 + fk];
        f32x4 acc = {0.f, 0.f, 0.f, 0.f};
        acc = __builtin_amdgcn_mfma_f32_16x16x32_f16(pa0, b0, acc, 0, 0, 0);
        acc = __builtin_amdgcn_mfma_f32_16x16x32_f16(pa1, b1, acc, 0, 0, 0);
        const int dk = 16 * j + fr;
#pragma unroll
        for (int r = 0; r < 4; ++r) {
            const int t = 16 * w + er + r;
            Zg[slot + t * 64 + dk] = (f16)(el[t] * (float)Ql[t * SF + dk] - acc[r]);
        }
    }
#pragma unroll
    for (int j = 0; j < 4; ++j) {
        f16x8 b0 = *(const f16x8*)&Xt[(16 * j + fr) * SF + fk];
        f16x8 b1 = *(const f16x8*)&Xt[(16 * j + fr) * SF + 32 + fk];
        f32x4 acc = {0.f, 0.f, 0.f, 0.f};
        acc = __builtin_amdgcn_mfma_f32_16x16x32_f16(ka0, b0, acc, 0, 0, 0);
        acc = __builtin_amdgcn_mfma_f32_16x16x32_f16(ka1, b1, acc, 0, 0, 0);
        const int dv = 16 * j + fr;
#pragma unroll
        for (int r = 0; r < 4; ++r) {
            const int dk = 16 * w + er + r;
            Hg[slot + dk * 64 + dv] = (f16)acc[r];
        }
    }
    const float e63v = el[63];
#pragma unroll
    for (int j = 0; j < 4; ++j) {
        f16x8 b0 = *(const f16x8*)&Xt[(64 + 16 * j + fr) * SF + fk];
        f16x8 b1 = *(const f16x8*)&Xt[(64 + 16 * j + fr) * SF + 32 + fk];
        f32x4 acc = {0.f, 0.f, 0.f, 0.f};
        acc = __builtin_amdgcn_mfma_f32_16x16x32_f16(ka0, b0, acc, 0, 0, 0);
        acc = __builtin_amdgcn_mfma_f32_16x16x32_f16(ka1, b1, acc, 0, 0, 0);
        const int dk2 = 16 * j + fr;
#pragma unroll
        for (int r = 0; r < 4; ++r) {
            const int dk = 16 * w + er + r;
            Gg[slot + dk * 64 + dk2] = (f16)(((dk == dk2) ? e63v : 0.f) - acc[r]);
        }
    }
}

// ---------------------------------------------------------------------------
// Delta scan: S' = G@S + H only. Block = (seq, head). (unchanged)
// ---------------------------------------------------------------------------
__global__ __launch_bounds__(256) void delta_scan(
        const int* __restrict__ cu, const f16* __restrict__ Gg,
        const f16* __restrict__ Hg, f16* __restrict__ Sc) {
    const int b = blockIdx.x >> 4, h = blockIdx.x & 15;
    const int tid = threadIdx.x;
    const int lane = tid & 63, w = tid >> 6;
    const int fr = lane & 15;
    const int fk = (lane >> 4) * 8;
    const int er = (lane >> 4) * 4;

    __shared__ __align__(16) f16 Sl[64 * SF];   // S^T [dv][dk]
    for (int i = tid; i < 64 * SF; i += 256) Sl[i] = (f16)0.f;

    int cs = 0;
    for (int i = 0; i < b; ++i) cs += ((cu[i + 1] - cu[i]) + 63) >> 6;
    const int t0 = cu[b], t1 = cu[b + 1];
    const int nb = (t1 - t0 + 63) >> 6;

    for (int ci = 0; ci < nb; ++ci) {
        const size_t slot = (size_t)((cs + ci) * 16 + h) * 4096;
        __syncthreads();  // Sl stable (init or prev S-write)

        {
            const int r = tid >> 2;
            const int c0 = (tid & 3) * 16;
            uint4 s0 = *(const uint4*)&Sl[r * SF + c0];
            uint4 s1 = *(const uint4*)&Sl[r * SF + c0 + 8];
            *(uint4*)&Sc[slot + r * 64 + c0] = s0;
            *(uint4*)&Sc[slot + r * 64 + c0 + 8] = s1;
        }

        f16x8 ga0 = *(const f16x8*)&Gg[slot + (16 * w + fr) * 64 + fk];
        f16x8 ga1 = *(const f16x8*)&Gg[slot + (16 * w + fr) * 64 + 32 + fk];
        f16x8 sb[4][2];
        f32x4 acc[4];
#pragma unroll
        for (int j = 0; j < 4; ++j) {
            sb[j][0] = *(const f16x8*)&Sl[(16 * j + fr) * SF + fk];
            sb[j][1] = *(const f16x8*)&Sl[(16 * j + fr) * SF + 32 + fk];
            const int dv = 16 * j + fr;
#pragma unroll
            for (int r = 0; r < 4; ++r)
                acc[j][r] = (float)Hg[slot + (16 * w + er + r) * 64 + dv];
        }
        __syncthreads();  // all Sl reads done before overwrite
#pragma unroll
        for (int j = 0; j < 4; ++j) {
            acc[j] = __builtin_amdgcn_mfma_f32_16x16x32_f16(ga0, sb[j][0], acc[j], 0, 0, 0);
            acc[j] = __builtin_amdgcn_mfma_f32_16x16x32_f16(ga1, sb[j][1], acc[j], 0, 0, 0);
            const int dv = 16 * j + fr;
#pragma unroll
            for (int r = 0; r < 4; ++r)
                Sl[dv * SF + 16 * w + er + r] = (f16)acc[j][r];  // S'^T
        }
    }
}

// ---------------------------------------------------------------------------
// Delta out: O = ob + Z@Sc, fused gated RMSNorm -> obf. (unchanged)
// ---------------------------------------------------------------------------
__global__ __launch_bounds__(256) void delta_out(
        const int* __restrict__ cu, const f16* __restrict__ Zg,
        const f16* __restrict__ Sc, const float* __restrict__ ob,
        const f16* __restrict__ mixed3, const float* __restrict__ nw,
        f16* __restrict__ obf) {
    const int c = blockIdx.x >> 4;
    const int h = blockIdx.x & 15;
    int b = -1, base = 0, t1 = 0, cs = 0;
    for (int i = 0; i < NSEQ; ++i) {
        int len = cu[i + 1] - cu[i];
        int nbc = (len + 63) >> 6;
        if (b < 0) {
            if (c < cs + nbc) { b = i; base = cu[i] + (c - cs) * 64; t1 = cu[i + 1]; }
            else cs += nbc;
        }
    }
    if (b < 0) return;
    const size_t slot = (size_t)blockIdx.x * 4096;

    const int tid = threadIdx.x;
    const int lane = tid & 63, w = tid >> 6;
    const int fr = lane & 15;
    const int fk = (lane >> 4) * 8;
    const int er = (lane >> 4) * 4;

    f16x8 za0 = *(const f16x8*)&Zg[slot + (16 * w + fr) * 64 + fk];
    f16x8 za1 = *(const f16x8*)&Zg[slot + (16 * w + fr) * 64 + 32 + fk];

    float oacc[4][4];
#pragma unroll
    for (int j = 0; j < 4; ++j) {
        f16x8 b0 = *(const f16x8*)&Sc[slot + (16 * j + fr) * 64 + fk];
        f16x8 b1 = *(const f16x8*)&Sc[slot + (16 * j + fr) * 64 + 32 + fk];
        f32x4 acc = {0.f, 0.f, 0.f, 0.f};
        acc = __builtin_amdgcn_mfma_f32_16x16x32_f16(za0, b0, acc, 0, 0, 0);
        acc = __builtin_amdgcn_mfma_f32_16x16x32_f16(za1, b1, acc, 0, 0, 0);
        const int dv = 16 * j + fr;
#pragma unroll
        for (int r = 0; r < 4; ++r) {
            const int tau = base + 16 * w + er + r;
            oacc[j][r] = (tau < t1)
                ? ob[(size_t)tau * VAL_DIM + h * 64 + dv] + acc[r] : 0.f;
        }
    }
    float ss[4];
#pragma unroll
    for (int r = 0; r < 4; ++r) {
        ss[r] = oacc[0][r] * oacc[0][r] + oacc[1][r] * oacc[1][r]
              + oacc[2][r] * oacc[2][r] + oacc[3][r] * oacc[3][r];
#pragma unroll
        for (int m = 1; m < 16; m <<= 1) ss[r] += __shfl_xor(ss[r], m);
    }
#pragma unroll
    for (int r = 0; r < 4; ++r) {
        const int tau = base + 16 * w + er + r;
        if (tau < t1) {
            const float rms = rsqrtf(ss[r] * (1.f / 64.f) + 1e-6f);
#pragma unroll
            for (int j = 0; j < 4; ++j) {
                const int col = 16 * j + fr;
                const float z = (float)mixed3[(size_t)tau * NMIX + 2048 + h * 64 + col];
                const float sz = z / (1.f + expf(-z));
                obf[(size_t)tau * VAL_DIM + h * 64 + col] =
                    (f16)(oacc[j][r] * rms * nw[col] * sz);
            }
        }
    }
}

// ---------------------------------------------------------------------------
extern "C" void kernel_launch(void* const* d_in, const int* in_sizes, int n_in,
                              void* d_out, int out_size, void* d_ws, size_t ws_size,
                              hipStream_t stream) {
    const float* H    = (const float*)d_in[0];
    const float* Wqkv = (const float*)d_in[1];
    const float* Wz   = (const float*)d_in[2];
    const float* Wb   = (const float*)d_in[3];
    const float* Wa   = (const float*)d_in[4];
    const float* cwt  = (const float*)d_in[5];
    const float* dtb  = (const float*)d_in[6];
    const float* Alog = (const float*)d_in[7];
    const float* nw   = (const float*)d_in[8];
    const float* Wout = (const float*)d_in[9];
    const int*   cu   = (const int*)d_in[10];
    float* out = (float*)d_out;

    // --- Workspace (no aliasing; ws_size ~268 MB) ---
    f16* mixed3 = (f16*)d_ws;                              // 1536*3072 f16 (qkv | z)
    float* obuf  = (float*)(mixed3 + (size_t)TOTAL * NMIX);// 1536*1024 f32
    float* lgbuf = obuf + (size_t)TOTAL * VAL_DIM;         // 1536*16
    float* bbuf  = lgbuf + (size_t)TOTAL * HV;             // 1536*16
    f16* Hb    = (f16*)(bbuf + (size_t)TOTAL * HV);        // 1536*1024
    f16* Wqkvb = Hb + (size_t)TOTAL * HIDDEN;              // 2048*1024
    f16* Wzb   = Wqkvb + (size_t)CONV_DIM * HIDDEN;        // 1024*1024 (contiguous)
    f16* Woutb = Wzb + (size_t)VAL_DIM * HIDDEN;           // 1024*1024
    f16* qbuf  = Woutb + (size_t)HIDDEN * VAL_DIM;         // 1536*512
    f16* kbuf  = qbuf + (size_t)TOTAL * KEY_DIM;           // 1536*512
    f16* vbuf  = kbuf + (size_t)TOTAL * KEY_DIM;           // 1536*1024
    f16* obf   = vbuf + (size_t)TOTAL * VAL_DIM;           // 1536*1024
    f16* Gg    = obf + (size_t)TOTAL * VAL_DIM;            // MAXCH*16*4096
    f16* Hg    = Gg + (size_t)MAXCH * 16 * 4096;
    f16* Zg    = Hg + (size_t)MAXCH * 16 * 4096;
    f16* Scg   = Zg + (size_t)MAXCH * 16 * 4096;           // entering states

    // 0) f16 conversions
    to_f16_all<<<5632, 256, 0, stream>>>(H, Wqkv, Wz, Wout, Hb);

    // 1) mixed3 = H @ [Wqkv;Wz]^T  (1536 x 3072) -> f16  (double-buffered)
    gemm_mfma<f16><<<dim3(NMIX / 128, TOTAL / 128), 256, 0, stream>>>(
        Hb, Wqkvb, mixed3, TOTAL, NMIX, HIDDEN);
    // 2) conv+silu+l2norm -> q,k,v (f16)  AND  beta / log-gamma (merged)
    conv_proj<<<TOTAL, 256, 0, stream>>>(mixed3, cwt, cu, H, Wb, Wa, dtb, Alog,
                                         qbuf, kbuf, vbuf, bbuf, lgbuf);
    // 3) delta phase 1 (chunk-parallel, MFMA)
    delta_phase1<<<MAXCH * 16, 256, 0, stream>>>(qbuf, kbuf, vbuf, lgbuf, bbuf,
                                                 cu, obuf, Gg, Hg, Zg);
    // 4) delta scan (serial part only): Sc per chunk
    delta_scan<<<NSEQ * HV, 256, 0, stream>>>(cu, Gg, Hg, Scg);
    // 5) delta out (parallel): O = ob + Z@Sc, fused gated RMSNorm -> obf
    delta_out<<<MAXCH * 16, 256, 0, stream>>>(cu, Zg, Scg, obuf, mixed3, nw, obf);
    // 6) out = obf @ W_out^T -> fp32 d_out  (double-buffered)
    gemm_mfma<float><<<dim3(HIDDEN / 128, TOTAL / 128), 256, 0, stream>>>(
        obf, Woutb, out, TOTAL, HIDDEN, VAL_DIM);
}